// Round 1
// baseline (21838.625 us; speedup 1.0000x reference)
//
#include <hip/hip_runtime.h>
#include <math.h>

// Problem constants
// B=2, C=128, H=192, W=192, NH=4, WS=8, HD=32, N=64, SHIFT=4, HID=512, NWIN=576
#define SCALEf 0.1767766952966369f  // 32^-0.5

// ---------------------------------------------------------------------------
// NCHW -> BHWC transpose for x / source / target
// grid (1152, 8, 3): x = p-tile (36864/32), y = b*4 + ctile, z = tensor
__global__ __launch_bounds__(256) void k_transpose(
    const float* __restrict__ x, const float* __restrict__ s, const float* __restrict__ t,
    float* __restrict__ xo, float* __restrict__ so, float* __restrict__ to)
{
    int which = blockIdx.z;
    const float* in = which == 0 ? x : (which == 1 ? s : t);
    float* out = which == 0 ? xo : (which == 1 ? so : to);
    __shared__ float tile[32][33];
    int by = blockIdx.y;
    int b = by >> 2;
    int c0 = (by & 3) * 32;
    int p0 = blockIdx.x * 32;
    int tx = threadIdx.x & 31;
    int ty = threadIdx.x >> 5;  // 0..7
    const float* ip = in + (size_t)b * 128 * 36864;
    #pragma unroll
    for (int k = 0; k < 4; ++k) {
        int c = c0 + ty + 8 * k;
        tile[ty + 8 * k][tx] = ip[(size_t)c * 36864 + p0 + tx];
    }
    __syncthreads();
    float* op = out + (size_t)b * 36864 * 128;
    #pragma unroll
    for (int k = 0; k < 4; ++k) {
        int p = p0 + ty + 8 * k;
        op[(size_t)p * 128 + c0 + tx] = tile[tx][ty + 8 * k];
    }
}

// ---------------------------------------------------------------------------
// Fold projection: W2 = pW @ mW  [128x128], b2 = pb @ mW [128]
// grid 65 x 256: blocks 0..63 -> W2, block 64 -> b2
__global__ __launch_bounds__(256) void k_fold_proj(
    const float* __restrict__ pW, const float* __restrict__ pb,
    const float* __restrict__ mW, float* __restrict__ W2, float* __restrict__ b2)
{
    if (blockIdx.x < 64) {
        int o = blockIdx.x * 256 + threadIdx.x;
        int i = o >> 7, c = o & 127;
        float acc = 0.f;
        for (int k = 0; k < 128; ++k) acc = fmaf(pW[i * 128 + k], mW[k * 128 + c], acc);
        W2[o] = acc;
    } else {
        int c = threadIdx.x;
        if (c < 128) {
            float acc = 0.f;
            for (int k = 0; k < 128; ++k) acc = fmaf(pb[k], mW[k * 128 + c], acc);
            b2[c] = acc;
        }
    }
}

// ---------------------------------------------------------------------------
// conv weight transpose: OIHW [128][256][3][3] -> [9][256][128] (co contiguous)
__global__ __launch_bounds__(256) void k_convw_t(const float* __restrict__ wsrc,
                                                 float* __restrict__ wdst)
{
    int idx = blockIdx.x * 256 + threadIdx.x;  // 294912 total
    int co = idx & 127;
    int ci = (idx >> 7) & 255;
    int k = idx >> 15;  // 0..8
    wdst[idx] = wsrc[(co * 256 + ci) * 9 + k];
}

// ---------------------------------------------------------------------------
// Fused window attention: one WG per (branch, window).
// LDS: k,v tiles (64 KB). q + online softmax in registers per (head,row).
// Ends with fused proj (folded pW@mW) + LayerNorm + shortcut add.
__global__ __launch_bounds__(256) void k_attn(
    const float* __restrict__ xh, const float* __restrict__ srcb, const float* __restrict__ tgtb,
    const float* __restrict__ qW, const float* __restrict__ qb,
    const float* __restrict__ kvW, const float* __restrict__ kvb,
    const float* __restrict__ relb, const float* __restrict__ W2, const float* __restrict__ b2,
    const float* __restrict__ g1, const float* __restrict__ b1,
    float* __restrict__ sa, float* __restrict__ ta, int shift)
{
    __shared__ float s_k[64 * 128];
    __shared__ float s_v[64 * 128];
    int gid = blockIdx.x;
    int branch = gid >= 1152;
    int wid = branch ? gid - 1152 : gid;
    const float* feat = branch ? tgtb : srcb;
    float* outb = branch ? ta : sa;
    int b = wid / 576;
    int wi = wid - b * 576;
    int wh = wi / 24, wwi = wi - wh * 24;
    int t = threadIdx.x;

    int tok = t >> 2, g = t & 3;
    int ti = tok >> 3, tj = tok & 7;
    int hh = wh * 8 + ti + shift; if (hh >= 192) hh -= 192;
    int wwp = wwi * 8 + tj + shift; if (wwp >= 192) wwp -= 192;
    size_t rowbase = (((size_t)b * 192 + hh) * 192 + wwp) * 128;

    // Phase 1: stage fw (K/V source rows) into s_k
    {
        const float4* fs = (const float4*)(feat + rowbase + g * 32);
        float4* fd = (float4*)(s_k + tok * 128 + g * 32);
        #pragma unroll
        for (int q4 = 0; q4 < 8; ++q4) fd[q4] = fs[q4];
    }
    __syncthreads();

    // Phase 2: k,v = fw @ kvW + kvb   (thread: token row, 32-col group)
    float kr[32], vr[32];
    #pragma unroll
    for (int c = 0; c < 32; ++c) { kr[c] = kvb[g * 32 + c]; vr[c] = kvb[128 + g * 32 + c]; }
    for (int kk = 0; kk < 128; ++kk) {
        float f = s_k[tok * 128 + kk];
        const float* wr = kvW + kk * 256 + g * 32;
        #pragma unroll
        for (int c = 0; c < 32; ++c) kr[c] = fmaf(f, wr[c], kr[c]);
        #pragma unroll
        for (int c = 0; c < 32; ++c) vr[c] = fmaf(f, wr[128 + c], vr[c]);
    }
    __syncthreads();  // all fw reads done before overwrite
    {
        float4* kd = (float4*)(s_k + tok * 128 + g * 32);
        float4* vd = (float4*)(s_v + tok * 128 + g * 32);
        #pragma unroll
        for (int c = 0; c < 8; ++c) { kd[c] = ((float4*)kr)[c]; vd[c] = ((float4*)vr)[c]; }
    }
    __syncthreads();

    // Phase 3: q-row + online softmax + P@V   (thread: head = wave, row = lane)
    int head = t >> 6, row = t & 63;
    int ho = head * 32;
    int ri = row >> 3, rj = row & 7;
    int qh = wh * 8 + ri + shift; if (qh >= 192) qh -= 192;
    int qw = wwi * 8 + rj + shift; if (qw >= 192) qw -= 192;
    const float* xrow = xh + (((size_t)b * 192 + qh) * 192 + qw) * 128;
    float qrow[32];
    #pragma unroll
    for (int d = 0; d < 32; ++d) qrow[d] = qb[ho + d];
    for (int kk = 0; kk < 128; ++kk) {
        float xv = xrow[kk];
        const float* wr = qW + kk * 128 + ho;
        #pragma unroll
        for (int d = 0; d < 32; ++d) qrow[d] = fmaf(xv, wr[d], qrow[d]);
    }
    #pragma unroll
    for (int d = 0; d < 32; ++d) qrow[d] *= SCALEf;

    int cnt_row = 0;
    if (shift) {
        int gh = wh * 8 + ri, gw = wwi * 8 + rj;
        cnt_row = ((gh < 184) ? 0 : (gh < 188 ? 3 : 6)) + ((gw < 184) ? 0 : (gw < 188 ? 1 : 2));
    }
    float m = -1e30f, l = 0.f;
    float orow[32];
    #pragma unroll
    for (int d = 0; d < 32; ++d) orow[d] = 0.f;
    for (int j = 0; j < 64; ++j) {
        const float* krow = s_k + j * 128 + ho;
        float sdot = 0.f;
        #pragma unroll
        for (int d = 0; d < 32; ++d) sdot = fmaf(qrow[d], krow[d], sdot);
        int dr = ri - (j >> 3) + 7, dc = rj - (j & 7) + 7;
        sdot += relb[(dr * 15 + dc) * 4 + head];
        if (shift) {
            int gh = wh * 8 + (j >> 3), gw = wwi * 8 + (j & 7);
            int cj = ((gh < 184) ? 0 : (gh < 188 ? 3 : 6)) + ((gw < 184) ? 0 : (gw < 188 ? 1 : 2));
            sdot += (cj != cnt_row) ? -100.0f : 0.0f;
        }
        float mn = fmaxf(m, sdot);
        float corr = __expf(m - mn);
        float p = __expf(sdot - mn);
        l = l * corr + p;
        const float* vrow = s_v + j * 128 + ho;
        #pragma unroll
        for (int d = 0; d < 32; ++d) orow[d] = fmaf(p, vrow[d], orow[d] * corr);
        m = mn;
    }
    float linv = 1.0f / l;
    #pragma unroll
    for (int d = 0; d < 32; ++d) orow[d] *= linv;
    __syncthreads();  // all k reads done before overwrite
    #pragma unroll
    for (int c4 = 0; c4 < 8; ++c4)
        ((float4*)(s_k + row * 128 + ho))[c4] = ((float4*)orow)[c4];
    __syncthreads();

    // Phase 4: y = attn_out @ W2 + b2; LN(y)*g1+b1 + shortcut; write
    float y[32];
    #pragma unroll
    for (int c = 0; c < 32; ++c) y[c] = b2[g * 32 + c];
    for (int kk = 0; kk < 128; ++kk) {
        float ov = s_k[tok * 128 + kk];
        const float* wr = W2 + kk * 128 + g * 32;
        #pragma unroll
        for (int c = 0; c < 32; ++c) y[c] = fmaf(ov, wr[c], y[c]);
    }
    float sm = 0.f, sq = 0.f;
    #pragma unroll
    for (int c = 0; c < 32; ++c) { sm += y[c]; sq = fmaf(y[c], y[c], sq); }
    sm += __shfl_xor(sm, 1); sq += __shfl_xor(sq, 1);
    sm += __shfl_xor(sm, 2); sq += __shfl_xor(sq, 2);
    float mean = sm * (1.0f / 128.0f);
    float var = sq * (1.0f / 128.0f) - mean * mean;
    float rstd = rsqrtf(var + 1e-5f);
    const float* srow = xh + rowbase;  // shortcut row == output row
    float* drow = outb + rowbase;
    #pragma unroll
    for (int c = 0; c < 32; ++c) {
        int col = g * 32 + c;
        drow[col] = fmaf((y[c] - mean) * rstd, g1[col], b1[col]) + srow[col];
    }
}

// ---------------------------------------------------------------------------
// Fused MLP: x += LN(gelu(x@f1W+f1b)@f2W+f2b)*g2+b2. 16 tokens per WG, in-place.
__global__ __launch_bounds__(256) void k_mlp(
    float* __restrict__ sa, float* __restrict__ ta,
    const float* __restrict__ f1W, const float* __restrict__ f1b,
    const float* __restrict__ f2W, const float* __restrict__ f2b,
    const float* __restrict__ g2, const float* __restrict__ b2n)
{
    const int XP = 132, HP = 516;
    __shared__ float s_x[16 * 132];
    __shared__ float s_h[16 * 516];
    int gid = blockIdx.x;
    float* buf = (gid < 4608) ? sa : ta;
    int tb = (gid < 4608 ? gid : gid - 4608) * 16;
    int t = threadIdx.x;
    {
        int tok = t >> 4, gg = t & 15;
        const float4* src = (const float4*)(buf + (size_t)(tb + tok) * 128 + gg * 8);
        float4* dst = (float4*)(s_x + tok * XP + gg * 8);
        dst[0] = src[0]; dst[1] = src[1];
    }
    __syncthreads();
    {
        int tok = t >> 4, cg = t & 15;  // 32 hidden cols per thread
        float acc[32];
        #pragma unroll
        for (int c = 0; c < 32; ++c) acc[c] = f1b[cg * 32 + c];
        for (int kk = 0; kk < 128; ++kk) {
            float xv = s_x[tok * XP + kk];
            const float* wr = f1W + kk * 512 + cg * 32;
            #pragma unroll
            for (int c = 0; c < 32; ++c) acc[c] = fmaf(xv, wr[c], acc[c]);
        }
        float* hd = s_h + tok * HP + cg * 32;
        #pragma unroll
        for (int c = 0; c < 32; ++c) {
            float u = acc[c];
            hd[c] = 0.5f * u * (1.0f + erff(u * 0.70710678118654752f));
        }
    }
    __syncthreads();
    {
        int tok = t >> 4, cg = t & 15;  // 8 out cols per thread
        float acc[8];
        #pragma unroll
        for (int c = 0; c < 8; ++c) acc[c] = f2b[cg * 8 + c];
        for (int kk = 0; kk < 512; ++kk) {
            float hv = s_h[tok * HP + kk];
            const float* wr = f2W + kk * 128 + cg * 8;
            #pragma unroll
            for (int c = 0; c < 8; ++c) acc[c] = fmaf(hv, wr[c], acc[c]);
        }
        float sm = 0.f, sq = 0.f;
        #pragma unroll
        for (int c = 0; c < 8; ++c) { sm += acc[c]; sq = fmaf(acc[c], acc[c], sq); }
        sm += __shfl_xor(sm, 1); sq += __shfl_xor(sq, 1);
        sm += __shfl_xor(sm, 2); sq += __shfl_xor(sq, 2);
        sm += __shfl_xor(sm, 4); sq += __shfl_xor(sq, 4);
        sm += __shfl_xor(sm, 8); sq += __shfl_xor(sq, 8);
        float mean = sm * (1.0f / 128.0f);
        float var = sq * (1.0f / 128.0f) - mean * mean;
        float rstd = rsqrtf(var + 1e-5f);
        float* drow = buf + (size_t)(tb + tok) * 128 + cg * 8;
        #pragma unroll
        for (int c = 0; c < 8; ++c) {
            int col = cg * 8 + c;
            drow[c] = s_x[tok * XP + col] + fmaf((acc[c] - mean) * rstd, g2[col], b2n[col]);
        }
    }
}

// ---------------------------------------------------------------------------
// 3x3 conv over cat(sa,ta) [256 ch] -> 128 ch, + bias + PReLU.
// 4x4 output tile per WG; 6x6x256 input patch in LDS; weights pre-transposed.
__global__ __launch_bounds__(256) void k_conv(
    const float* __restrict__ sa, const float* __restrict__ ta,
    const float* __restrict__ wT, const float* __restrict__ bias,
    const float* __restrict__ pa, float* __restrict__ out, int nchw)
{
    __shared__ float s_in[36 * 260];
    int gid = blockIdx.x;
    int b = gid / 2304;
    int r = gid - b * 2304;
    int th = r / 48, tw = r - th * 48;
    int h0 = th * 4, w0 = tw * 4;
    for (int idx = threadIdx.x; idx < 36 * 64; idx += 256) {
        int prow = idx >> 6, gg = idx & 63;
        int ph = prow / 6, pw = prow - ph * 6;
        int h = h0 - 1 + ph, w = w0 - 1 + pw;
        float4 v = make_float4(0.f, 0.f, 0.f, 0.f);
        if (h >= 0 && h < 192 && w >= 0 && w < 192) {
            const float* src = ((gg < 32) ? sa : ta) + (((size_t)b * 192 + h) * 192 + w) * 128 + (gg & 31) * 4;
            v = *(const float4*)src;
        }
        *(float4*)(s_in + prow * 260 + gg * 4) = v;
    }
    __syncthreads();
    int pos = threadIdx.x >> 4;
    int ohl = pos >> 2, owl = pos & 3;
    int cg = threadIdx.x & 15;
    float acc[8];
    #pragma unroll
    for (int c = 0; c < 8; ++c) acc[c] = bias[cg * 8 + c];
    #pragma unroll
    for (int kh = 0; kh < 3; ++kh)
    #pragma unroll
    for (int kw = 0; kw < 3; ++kw) {
        const float* inb = s_in + ((ohl + kh) * 6 + (owl + kw)) * 260;
        const float* wb = wT + (size_t)(kh * 3 + kw) * 256 * 128 + cg * 8;
        for (int ci = 0; ci < 256; ++ci) {
            float iv = inb[ci];
            const float* wr = wb + ci * 128;
            #pragma unroll
            for (int c = 0; c < 8; ++c) acc[c] = fmaf(iv, wr[c], acc[c]);
        }
    }
    int oh = h0 + ohl, ow = w0 + owl;
    if (nchw) {
        #pragma unroll
        for (int c = 0; c < 8; ++c) {
            int co = cg * 8 + c;
            float v = acc[c];
            v = (v >= 0.f) ? v : pa[co] * v;
            out[(((size_t)b * 128 + co) * 192 + oh) * 192 + ow] = v;
        }
    } else {
        size_t basep = (((size_t)b * 192 + oh) * 192 + ow) * 128 + cg * 8;
        #pragma unroll
        for (int c = 0; c < 8; ++c) {
            int co = cg * 8 + c;
            float v = acc[c];
            v = (v >= 0.f) ? v : pa[co] * v;
            out[basep + c] = v;
        }
    }
}

// ---------------------------------------------------------------------------
extern "C" void kernel_launch(void* const* d_in, const int* in_sizes, int n_in,
                              void* d_out, int out_size, void* d_ws, size_t ws_size,
                              hipStream_t stream)
{
    const float* x    = (const float*)d_in[0];
    const float* src  = (const float*)d_in[1];
    const float* tgt  = (const float*)d_in[2];
    const float* qW   = (const float*)d_in[3];
    const float* qb   = (const float*)d_in[4];
    const float* kvW  = (const float*)d_in[5];
    const float* kvb  = (const float*)d_in[6];
    const float* pW   = (const float*)d_in[7];
    const float* pb   = (const float*)d_in[8];
    const float* relb = (const float*)d_in[9];
    const float* mW   = (const float*)d_in[10];
    const float* n1g  = (const float*)d_in[11];
    const float* n1b  = (const float*)d_in[12];
    const float* f1W  = (const float*)d_in[13];
    const float* f1b  = (const float*)d_in[14];
    const float* f2W  = (const float*)d_in[15];
    const float* f2b  = (const float*)d_in[16];
    const float* n2g  = (const float*)d_in[17];
    const float* n2b  = (const float*)d_in[18];
    const float* convW= (const float*)d_in[19];
    const float* convb= (const float*)d_in[20];
    const float* pa   = (const float*)d_in[21];
    float* out = (float*)d_out;

    const size_t FR = (size_t)2 * 192 * 192 * 128;  // 9437184 floats per BHWC tensor
    float* ws   = (float*)d_ws;
    float* xh   = ws;
    float* srch = ws + FR;
    float* tgth = ws + 2 * FR;
    float* sab  = ws + 3 * FR;
    float* tab  = ws + 4 * FR;
    float* W2   = ws + 5 * FR;
    float* b2   = W2 + 128 * 128;
    float* cwt  = b2 + 128;

    k_transpose<<<dim3(1152, 8, 3), 256, 0, stream>>>(x, src, tgt, xh, srch, tgth);

    for (int d = 0; d < 2; ++d) {
        int shift = d ? 4 : 0;
        k_fold_proj<<<65, 256, 0, stream>>>(pW + d * 16384, pb + d * 128, mW + d * 16384, W2, b2);
        k_convw_t<<<1152, 256, 0, stream>>>(convW + d * 294912, cwt);
        k_attn<<<2304, 256, 0, stream>>>(xh, srch, tgth,
            qW + d * 16384, qb + d * 128, kvW + d * 32768, kvb + d * 256,
            relb + d * 900, W2, b2, n1g + d * 128, n1b + d * 128, sab, tab, shift);
        k_mlp<<<9216, 256, 0, stream>>>(sab, tab, f1W + d * 65536, f1b + d * 512,
            f2W + d * 65536, f2b + d * 128, n2g + d * 128, n2b + d * 128);
        k_conv<<<4608, 256, 0, stream>>>(sab, tab, cwt, convb + d * 128, pa + d * 128,
            d == 1 ? out : xh, d == 1 ? 1 : 0);
    }
}

// Round 2
// 8686.344 us; speedup vs baseline: 2.5141x; 2.5141x over previous
//
#include <hip/hip_runtime.h>
#include <math.h>

// B=2, C=128, H=192, W=192, NH=4, WS=8, HD=32, N=64, SHIFT=4, HID=512, NWIN=576
#define SCALEf 0.1767766952966369f  // 32^-0.5

typedef short s16x8 __attribute__((ext_vector_type(8)));
typedef float f32x4 __attribute__((ext_vector_type(4)));

__device__ __forceinline__ short f2bf(float f) {
    unsigned u = __float_as_uint(f);
    u += 0x7FFF + ((u >> 16) & 1);
    return (short)(u >> 16);
}
__device__ __forceinline__ float gelu_f(float u) {
    // tanh-approx gelu: u * sigmoid(1.5957691 * u * (1 + 0.044715 u^2))
    float z = 1.5957691216057308f * u * (1.0f + 0.044715f * u * u);
    return u / (1.0f + __expf(-z));
}

// ---------------------------------------------------------------------------
// NCHW -> BHWC transpose for x / source / target
__global__ __launch_bounds__(256) void k_transpose(
    const float* __restrict__ x, const float* __restrict__ s, const float* __restrict__ t,
    float* __restrict__ xo, float* __restrict__ so, float* __restrict__ to)
{
    int which = blockIdx.z;
    const float* in = which == 0 ? x : (which == 1 ? s : t);
    float* out = which == 0 ? xo : (which == 1 ? so : to);
    __shared__ float tile[32][33];
    int by = blockIdx.y;
    int b = by >> 2;
    int c0 = (by & 3) * 32;
    int p0 = blockIdx.x * 32;
    int tx = threadIdx.x & 31;
    int ty = threadIdx.x >> 5;
    const float* ip = in + (size_t)b * 128 * 36864;
    #pragma unroll
    for (int k = 0; k < 4; ++k) {
        int c = c0 + ty + 8 * k;
        tile[ty + 8 * k][tx] = ip[(size_t)c * 36864 + p0 + tx];
    }
    __syncthreads();
    float* op = out + (size_t)b * 36864 * 128;
    #pragma unroll
    for (int k = 0; k < 4; ++k) {
        int p = p0 + ty + 8 * k;
        op[(size_t)p * 128 + c0 + tx] = tile[tx][ty + 8 * k];
    }
}

// ---------------------------------------------------------------------------
// Fold projection: W2 = pW @ mW  [128x128], b2 = pb @ mW [128]   (fp32, for attn)
__global__ __launch_bounds__(256) void k_fold_proj(
    const float* __restrict__ pW, const float* __restrict__ pb,
    const float* __restrict__ mW, float* __restrict__ W2, float* __restrict__ b2)
{
    if (blockIdx.x < 64) {
        int o = blockIdx.x * 256 + threadIdx.x;
        int i = o >> 7, c = o & 127;
        float acc = 0.f;
        for (int k = 0; k < 128; ++k) acc = fmaf(pW[i * 128 + k], mW[k * 128 + c], acc);
        W2[o] = acc;
    } else {
        int c = threadIdx.x;
        if (c < 128) {
            float acc = 0.f;
            for (int k = 0; k < 128; ++k) acc = fmaf(pb[k], mW[k * 128 + c], acc);
            b2[c] = acc;
        }
    }
}

// ---------------------------------------------------------------------------
// Weight prep (per depth): bf16-transposed MLP weights + conv weights
// W1T[n*128+k] = f1W[k*512+n]   (512x128)
// W2T[n*512+k] = f2W[k*128+n]   (128x512)
// cwb[(k9*128+co)*256+ci] = convW[(co*256+ci)*9+k9]
__global__ __launch_bounds__(256) void k_prep(
    const float* __restrict__ f1W, const float* __restrict__ f2W,
    const float* __restrict__ convW,
    short* __restrict__ W1T, short* __restrict__ W2T, short* __restrict__ cwb)
{
    int idx = blockIdx.x * 256 + threadIdx.x;
    if (idx < 65536) {
        int n = idx >> 7, k = idx & 127;
        W1T[idx] = f2bf(f1W[k * 512 + n]);
    } else if (idx < 131072) {
        int j = idx - 65536;
        int n = j >> 9, k = j & 511;
        W2T[j] = f2bf(f2W[k * 128 + n]);
    } else {
        int j = idx - 131072;  // 0..294911
        int ci = j & 255;
        int co = (j >> 8) & 127;
        int k9 = j >> 15;
        cwb[j] = f2bf(convW[(co * 256 + ci) * 9 + k9]);
    }
}

// ---------------------------------------------------------------------------
// Fused window attention (unchanged fp32 path from round 1)
__global__ __launch_bounds__(256) void k_attn(
    const float* __restrict__ xh, const float* __restrict__ srcb, const float* __restrict__ tgtb,
    const float* __restrict__ qW, const float* __restrict__ qb,
    const float* __restrict__ kvW, const float* __restrict__ kvb,
    const float* __restrict__ relb, const float* __restrict__ W2, const float* __restrict__ b2,
    const float* __restrict__ g1, const float* __restrict__ b1,
    float* __restrict__ sa, float* __restrict__ ta, int shift)
{
    __shared__ float s_k[64 * 128];
    __shared__ float s_v[64 * 128];
    int gid = blockIdx.x;
    int branch = gid >= 1152;
    int wid = branch ? gid - 1152 : gid;
    const float* feat = branch ? tgtb : srcb;
    float* outb = branch ? ta : sa;
    int b = wid / 576;
    int wi = wid - b * 576;
    int wh = wi / 24, wwi = wi - wh * 24;
    int t = threadIdx.x;

    int tok = t >> 2, g = t & 3;
    int ti = tok >> 3, tj = tok & 7;
    int hh = wh * 8 + ti + shift; if (hh >= 192) hh -= 192;
    int wwp = wwi * 8 + tj + shift; if (wwp >= 192) wwp -= 192;
    size_t rowbase = (((size_t)b * 192 + hh) * 192 + wwp) * 128;

    {
        const float4* fs = (const float4*)(feat + rowbase + g * 32);
        float4* fd = (float4*)(s_k + tok * 128 + g * 32);
        #pragma unroll
        for (int q4 = 0; q4 < 8; ++q4) fd[q4] = fs[q4];
    }
    __syncthreads();

    float kr[32], vr[32];
    #pragma unroll
    for (int c = 0; c < 32; ++c) { kr[c] = kvb[g * 32 + c]; vr[c] = kvb[128 + g * 32 + c]; }
    for (int kk = 0; kk < 128; ++kk) {
        float f = s_k[tok * 128 + kk];
        const float* wr = kvW + kk * 256 + g * 32;
        #pragma unroll
        for (int c = 0; c < 32; ++c) kr[c] = fmaf(f, wr[c], kr[c]);
        #pragma unroll
        for (int c = 0; c < 32; ++c) vr[c] = fmaf(f, wr[128 + c], vr[c]);
    }
    __syncthreads();
    {
        float4* kd = (float4*)(s_k + tok * 128 + g * 32);
        float4* vd = (float4*)(s_v + tok * 128 + g * 32);
        #pragma unroll
        for (int c = 0; c < 8; ++c) { kd[c] = ((float4*)kr)[c]; vd[c] = ((float4*)vr)[c]; }
    }
    __syncthreads();

    int head = t >> 6, row = t & 63;
    int ho = head * 32;
    int ri = row >> 3, rj = row & 7;
    int qh = wh * 8 + ri + shift; if (qh >= 192) qh -= 192;
    int qw = wwi * 8 + rj + shift; if (qw >= 192) qw -= 192;
    const float* xrow = xh + (((size_t)b * 192 + qh) * 192 + qw) * 128;
    float qrow[32];
    #pragma unroll
    for (int d = 0; d < 32; ++d) qrow[d] = qb[ho + d];
    for (int kk = 0; kk < 128; ++kk) {
        float xv = xrow[kk];
        const float* wr = qW + kk * 128 + ho;
        #pragma unroll
        for (int d = 0; d < 32; ++d) qrow[d] = fmaf(xv, wr[d], qrow[d]);
    }
    #pragma unroll
    for (int d = 0; d < 32; ++d) qrow[d] *= SCALEf;

    int cnt_row = 0;
    if (shift) {
        int gh = wh * 8 + ri, gw = wwi * 8 + rj;
        cnt_row = ((gh < 184) ? 0 : (gh < 188 ? 3 : 6)) + ((gw < 184) ? 0 : (gw < 188 ? 1 : 2));
    }
    float m = -1e30f, l = 0.f;
    float orow[32];
    #pragma unroll
    for (int d = 0; d < 32; ++d) orow[d] = 0.f;
    for (int j = 0; j < 64; ++j) {
        const float* krow = s_k + j * 128 + ho;
        float sdot = 0.f;
        #pragma unroll
        for (int d = 0; d < 32; ++d) sdot = fmaf(qrow[d], krow[d], sdot);
        int dr = ri - (j >> 3) + 7, dc = rj - (j & 7) + 7;
        sdot += relb[(dr * 15 + dc) * 4 + head];
        if (shift) {
            int gh = wh * 8 + (j >> 3), gw = wwi * 8 + (j & 7);
            int cj = ((gh < 184) ? 0 : (gh < 188 ? 3 : 6)) + ((gw < 184) ? 0 : (gw < 188 ? 1 : 2));
            sdot += (cj != cnt_row) ? -100.0f : 0.0f;
        }
        float mn = fmaxf(m, sdot);
        float corr = __expf(m - mn);
        float p = __expf(sdot - mn);
        l = l * corr + p;
        const float* vrow = s_v + j * 128 + ho;
        #pragma unroll
        for (int d = 0; d < 32; ++d) orow[d] = fmaf(p, vrow[d], orow[d] * corr);
        m = mn;
    }
    float linv = 1.0f / l;
    #pragma unroll
    for (int d = 0; d < 32; ++d) orow[d] *= linv;
    __syncthreads();
    #pragma unroll
    for (int c4 = 0; c4 < 8; ++c4)
        ((float4*)(s_k + row * 128 + ho))[c4] = ((float4*)orow)[c4];
    __syncthreads();

    float y[32];
    #pragma unroll
    for (int c = 0; c < 32; ++c) y[c] = b2[g * 32 + c];
    for (int kk = 0; kk < 128; ++kk) {
        float ov = s_k[tok * 128 + kk];
        const float* wr = W2 + kk * 128 + g * 32;
        #pragma unroll
        for (int c = 0; c < 32; ++c) y[c] = fmaf(ov, wr[c], y[c]);
    }
    float sm = 0.f, sq = 0.f;
    #pragma unroll
    for (int c = 0; c < 32; ++c) { sm += y[c]; sq = fmaf(y[c], y[c], sq); }
    sm += __shfl_xor(sm, 1); sq += __shfl_xor(sq, 1);
    sm += __shfl_xor(sm, 2); sq += __shfl_xor(sq, 2);
    float mean = sm * (1.0f / 128.0f);
    float var = sq * (1.0f / 128.0f) - mean * mean;
    float rstd = rsqrtf(var + 1e-5f);
    const float* srow = xh + rowbase;
    float* drow = outb + rowbase;
    #pragma unroll
    for (int c = 0; c < 32; ++c) {
        int col = g * 32 + c;
        drow[col] = fmaf((y[c] - mean) * rstd, g1[col], b1[col]) + srow[col];
    }
}

// ---------------------------------------------------------------------------
// MFMA MLP: per 16-token tile per wave, both branches in one block.
// GEMM1 (K=128) -> gelu -> bf16 H in wave-private LDS -> GEMM2 (K=512)
// -> LN + residual -> write bf16 into cat buffer (aliased onto sab!).
// Block = 256 thr = 4 waves, 64 tokens; grid = 1152.
__global__ __launch_bounds__(256) void k_mlp_mfma(
    const float* sab, const float* tab,
    const short* __restrict__ W1T, const float* __restrict__ f1b,
    const short* __restrict__ W2T, const float* __restrict__ f2b,
    const float* __restrict__ g2, const float* __restrict__ b2n,
    short* catb)
{
    __shared__ short s_h[4][16 * 520];   // 520 = 512 + 8 pad (bank stagger)
    int w = threadIdx.x >> 6, lane = threadIdx.x & 63;
    int ln = lane & 15, quad = lane >> 4;
    int tok0 = blockIdx.x * 64 + w * 16;
    short* H = s_h[w];

    for (int br = 0; br < 2; ++br) {
        const float* X = br ? tab : sab;
        // A fragments: X[tok0+ln][kc*32 + quad*8 .. +8] as bf16
        s16x8 a1[4];
        const float* xrow = X + (size_t)(tok0 + ln) * 128 + quad * 8;
        #pragma unroll
        for (int kc = 0; kc < 4; ++kc) {
            float4 u0 = *(const float4*)(xrow + kc * 32);
            float4 u1 = *(const float4*)(xrow + kc * 32 + 4);
            s16x8 a;
            a[0] = f2bf(u0.x); a[1] = f2bf(u0.y); a[2] = f2bf(u0.z); a[3] = f2bf(u0.w);
            a[4] = f2bf(u1.x); a[5] = f2bf(u1.y); a[6] = f2bf(u1.z); a[7] = f2bf(u1.w);
            a1[kc] = a;
        }
        // GEMM1: 16 x 512, K=128
        for (int nt = 0; nt < 32; ++nt) {
            f32x4 acc = {0.f, 0.f, 0.f, 0.f};
            const short* wb = W1T + (nt * 16 + ln) * 128 + quad * 8;
            #pragma unroll
            for (int kc = 0; kc < 4; ++kc) {
                s16x8 bfr = *(const s16x8*)(wb + kc * 32);
                acc = __builtin_amdgcn_mfma_f32_16x16x32_bf16(a1[kc], bfr, acc, 0, 0, 0);
            }
            float bb = f1b[nt * 16 + ln];
            #pragma unroll
            for (int r = 0; r < 4; ++r)
                H[(quad * 4 + r) * 520 + nt * 16 + ln] = f2bf(gelu_f(acc[r] + bb));
        }
        // GEMM2: 16 x 128, K=512
        f32x4 acc2[8];
        #pragma unroll
        for (int nt = 0; nt < 8; ++nt) acc2[nt] = (f32x4){0.f, 0.f, 0.f, 0.f};
        for (int kc = 0; kc < 16; ++kc) {
            s16x8 afr = *(const s16x8*)(H + ln * 520 + kc * 32 + quad * 8);
            #pragma unroll
            for (int nt = 0; nt < 8; ++nt) {
                s16x8 bfr = *(const s16x8*)(W2T + (nt * 16 + ln) * 512 + kc * 32 + quad * 8);
                acc2[nt] = __builtin_amdgcn_mfma_f32_16x16x32_bf16(afr, bfr, acc2[nt], 0, 0, 0);
            }
        }
        // bias
        #pragma unroll
        for (int nt = 0; nt < 8; ++nt) {
            float bb = f2b[nt * 16 + ln];
            #pragma unroll
            for (int r = 0; r < 4; ++r) acc2[nt][r] += bb;
        }
        // LN + residual + bf16 cat write (row = token, col = lane&15 + 16*nt)
        #pragma unroll
        for (int r = 0; r < 4; ++r) {
            float smv = 0.f, sqv = 0.f;
            #pragma unroll
            for (int nt = 0; nt < 8; ++nt) { float v = acc2[nt][r]; smv += v; sqv = fmaf(v, v, sqv); }
            smv += __shfl_xor(smv, 1); sqv += __shfl_xor(sqv, 1);
            smv += __shfl_xor(smv, 2); sqv += __shfl_xor(sqv, 2);
            smv += __shfl_xor(smv, 4); sqv += __shfl_xor(sqv, 4);
            smv += __shfl_xor(smv, 8); sqv += __shfl_xor(sqv, 8);
            float mean = smv * (1.0f / 128.0f);
            float var = sqv * (1.0f / 128.0f) - mean * mean;
            float rstd = rsqrtf(var + 1e-5f);
            int row = tok0 + quad * 4 + r;
            const float* xr = X + (size_t)row * 128;
            short* cb = catb + (size_t)row * 256 + br * 128;
            #pragma unroll
            for (int nt = 0; nt < 8; ++nt) {
                int col = nt * 16 + ln;
                float o = xr[col] + fmaf((acc2[nt][r] - mean) * rstd, g2[col], b2n[col]);
                cb[col] = f2bf(o);
            }
        }
    }
}

// ---------------------------------------------------------------------------
// MFMA implicit-GEMM conv3x3 (256->128) + bias + PReLU over bf16 cat buffer.
// Block: 32 positions (one h row, w0..w0+31) x 128 cout; 4 waves:
// wave = (ngrp = w>>1 : 64 cols) x (mt = w&1 : 16 positions).
// grid = 2304 (b x 192 x 6).
__global__ __launch_bounds__(256) void k_conv_mfma(
    const short* __restrict__ catb, const short* __restrict__ cwb,
    const float* __restrict__ bias, const float* __restrict__ pa,
    float* __restrict__ out, int nchw)
{
    __shared__ short s_in[3 * 34 * 264];   // 264 = 256 + 8 pad
    __shared__ float s_out[128 * 33];
    int gid = blockIdx.x;
    int b = gid / 1152;
    int r0 = gid - b * 1152;
    int h = r0 / 6;
    int w0 = (r0 - h * 6) * 32;
    int tid = threadIdx.x;

    // stage 3x34x256 bf16 patch
    for (int idx = tid; idx < 3264; idx += 256) {
        int row = idx >> 5, seg = idx & 31;
        int dh = row / 34, wc34 = row - dh * 34;
        int hh = h - 1 + dh;
        int wc = w0 - 1 + wc34;
        uint4 v = make_uint4(0u, 0u, 0u, 0u);
        if (hh >= 0 && hh < 192 && wc >= 0 && wc < 192)
            v = *(const uint4*)(catb + (((size_t)b * 192 + hh) * 192 + wc) * 256 + seg * 8);
        *(uint4*)(&s_in[(dh * 34 + wc34) * 264 + seg * 8]) = v;
    }
    __syncthreads();

    int w = tid >> 6, lane = tid & 63;
    int ln = lane & 15, quad = lane >> 4;
    int mt = w & 1, ng = w >> 1;
    f32x4 acc[4];
    #pragma unroll
    for (int nt = 0; nt < 4; ++nt) acc[nt] = (f32x4){0.f, 0.f, 0.f, 0.f};

    #pragma unroll
    for (int kh = 0; kh < 3; ++kh) {
        #pragma unroll
        for (int kw = 0; kw < 3; ++kw) {
            int pc = mt * 16 + ln + kw;
            const short* abase = &s_in[(kh * 34 + pc) * 264];
            const short* wbase = cwb + (size_t)((kh * 3 + kw) * 128 + ng * 64) * 256;
            for (int kc = 0; kc < 8; ++kc) {
                s16x8 afr = *(const s16x8*)(abase + kc * 32 + quad * 8);
                #pragma unroll
                for (int nt = 0; nt < 4; ++nt) {
                    s16x8 bfr = *(const s16x8*)(wbase + (nt * 16 + ln) * 256 + kc * 32 + quad * 8);
                    acc[nt] = __builtin_amdgcn_mfma_f32_16x16x32_bf16(afr, bfr, acc[nt], 0, 0, 0);
                }
            }
        }
    }

    if (nchw) {
        #pragma unroll
        for (int nt = 0; nt < 4; ++nt) {
            int co = ng * 64 + nt * 16 + ln;
            float bs = bias[co], pv = pa[co];
            #pragma unroll
            for (int r = 0; r < 4; ++r) {
                int pos = mt * 16 + quad * 4 + r;
                float v = acc[nt][r] + bs;
                v = (v >= 0.f) ? v : pv * v;
                s_out[co * 33 + pos] = v;
            }
        }
        __syncthreads();
        for (int idx = tid; idx < 1024; idx += 256) {
            int co = idx >> 3, sg = idx & 7;
            float4 v;
            v.x = s_out[co * 33 + sg * 4 + 0];
            v.y = s_out[co * 33 + sg * 4 + 1];
            v.z = s_out[co * 33 + sg * 4 + 2];
            v.w = s_out[co * 33 + sg * 4 + 3];
            *(float4*)(out + (((size_t)b * 128 + co) * 192 + h) * 192 + w0 + sg * 4) = v;
        }
    } else {
        #pragma unroll
        for (int nt = 0; nt < 4; ++nt) {
            int co = ng * 64 + nt * 16 + ln;
            float bs = bias[co], pv = pa[co];
            #pragma unroll
            for (int r = 0; r < 4; ++r) {
                int pos = mt * 16 + quad * 4 + r;
                float v = acc[nt][r] + bs;
                v = (v >= 0.f) ? v : pv * v;
                out[(((size_t)b * 192 + h) * 192 + w0 + pos) * 128 + co] = v;
            }
        }
    }
}

// ---------------------------------------------------------------------------
extern "C" void kernel_launch(void* const* d_in, const int* in_sizes, int n_in,
                              void* d_out, int out_size, void* d_ws, size_t ws_size,
                              hipStream_t stream)
{
    const float* x    = (const float*)d_in[0];
    const float* src  = (const float*)d_in[1];
    const float* tgt  = (const float*)d_in[2];
    const float* qW   = (const float*)d_in[3];
    const float* qb   = (const float*)d_in[4];
    const float* kvW  = (const float*)d_in[5];
    const float* kvb  = (const float*)d_in[6];
    const float* pW   = (const float*)d_in[7];
    const float* pb   = (const float*)d_in[8];
    const float* relb = (const float*)d_in[9];
    const float* mW   = (const float*)d_in[10];
    const float* n1g  = (const float*)d_in[11];
    const float* n1b  = (const float*)d_in[12];
    const float* f1W  = (const float*)d_in[13];
    const float* f1b  = (const float*)d_in[14];
    const float* f2W  = (const float*)d_in[15];
    const float* f2b  = (const float*)d_in[16];
    const float* n2g  = (const float*)d_in[17];
    const float* n2b  = (const float*)d_in[18];
    const float* convW= (const float*)d_in[19];
    const float* convb= (const float*)d_in[20];
    const float* pa   = (const float*)d_in[21];
    float* out = (float*)d_out;

    const size_t FR = (size_t)2 * 192 * 192 * 128;  // floats per BHWC tensor
    float* ws   = (float*)d_ws;
    float* xh   = ws;
    float* srch = ws + FR;
    float* tgth = ws + 2 * FR;
    float* sab  = ws + 3 * FR;
    float* tab  = ws + 4 * FR;
    float* W2   = ws + 5 * FR;
    float* b2   = W2 + 16384;
    short* W1T  = (short*)(b2 + 128);        // 65536 shorts
    short* W2T  = W1T + 65536;               // 65536 shorts
    short* cwb  = W2T + 65536;               // 294912 shorts
    short* catb = (short*)sab;               // bf16 cat buffer aliases sab

    k_transpose<<<dim3(1152, 8, 3), 256, 0, stream>>>(x, src, tgt, xh, srch, tgth);

    for (int d = 0; d < 2; ++d) {
        int shift = d ? 4 : 0;
        k_fold_proj<<<65, 256, 0, stream>>>(pW + d * 16384, pb + d * 128, mW + d * 16384, W2, b2);
        k_prep<<<1664, 256, 0, stream>>>(f1W + d * 65536, f2W + d * 65536,
                                         convW + d * 294912, W1T, W2T, cwb);
        k_attn<<<2304, 256, 0, stream>>>(xh, srch, tgth,
            qW + d * 16384, qb + d * 128, kvW + d * 32768, kvb + d * 256,
            relb + d * 900, W2, b2, n1g + d * 128, n1b + d * 128, sab, tab, shift);
        k_mlp_mfma<<<1152, 256, 0, stream>>>(sab, tab, W1T, f1b + d * 512,
            W2T, f2b + d * 128, n2g + d * 128, n2b + d * 128, catb);
        k_conv_mfma<<<2304, 256, 0, stream>>>(catb, cwb, convb + d * 128, pa + d * 128,
            d == 1 ? out : xh, d == 1 ? 1 : 0);
    }
}

// Round 3
// 2437.139 us; speedup vs baseline: 8.9608x; 3.5642x over previous
//
#include <hip/hip_runtime.h>
#include <math.h>

// B=2, C=128, H=192, W=192, NH=4, WS=8, HD=32, N=64, SHIFT=4, HID=512, NWIN=576
#define SCALEf 0.1767766952966369f  // 32^-0.5

typedef short s16x8 __attribute__((ext_vector_type(8)));
typedef float f32x4 __attribute__((ext_vector_type(4)));

__device__ __forceinline__ short f2bf(float f) {
    unsigned u = __float_as_uint(f);
    u += 0x7FFF + ((u >> 16) & 1);
    return (short)(u >> 16);
}
__device__ __forceinline__ float gelu_f(float u) {
    float z = 1.5957691216057308f * u * (1.0f + 0.044715f * u * u);
    return u / (1.0f + __expf(-z));
}
// load 8 consecutive floats, convert to bf16 fragment
__device__ __forceinline__ s16x8 ld8bf(const float* p) {
    float4 u0 = *(const float4*)p;
    float4 u1 = *(const float4*)(p + 4);
    s16x8 a;
    a[0] = f2bf(u0.x); a[1] = f2bf(u0.y); a[2] = f2bf(u0.z); a[3] = f2bf(u0.w);
    a[4] = f2bf(u1.x); a[5] = f2bf(u1.y); a[6] = f2bf(u1.z); a[7] = f2bf(u1.w);
    return a;
}
__device__ __forceinline__ int region_code(int h, int w) {
    return ((h < 184) ? 0 : (h < 188 ? 3 : 6)) + ((w < 184) ? 0 : (w < 188 ? 1 : 2));
}

// ---------------------------------------------------------------------------
// NCHW -> BHWC transpose for x / source / target
__global__ __launch_bounds__(256) void k_transpose(
    const float* __restrict__ x, const float* __restrict__ s, const float* __restrict__ t,
    float* __restrict__ xo, float* __restrict__ so, float* __restrict__ to)
{
    int which = blockIdx.z;
    const float* in = which == 0 ? x : (which == 1 ? s : t);
    float* out = which == 0 ? xo : (which == 1 ? so : to);
    __shared__ float tile[32][33];
    int by = blockIdx.y;
    int b = by >> 2;
    int c0 = (by & 3) * 32;
    int p0 = blockIdx.x * 32;
    int tx = threadIdx.x & 31;
    int ty = threadIdx.x >> 5;
    const float* ip = in + (size_t)b * 128 * 36864;
    #pragma unroll
    for (int k = 0; k < 4; ++k) {
        int c = c0 + ty + 8 * k;
        tile[ty + 8 * k][tx] = ip[(size_t)c * 36864 + p0 + tx];
    }
    __syncthreads();
    float* op = out + (size_t)b * 36864 * 128;
    #pragma unroll
    for (int k = 0; k < 4; ++k) {
        int p = p0 + ty + 8 * k;
        op[(size_t)p * 128 + c0 + tx] = tile[tx][ty + 8 * k];
    }
}

// ---------------------------------------------------------------------------
// Fold projection: W2 = pW @ mW; write bf16 W2T[n][k] + fp32 b2 = pb @ mW
__global__ __launch_bounds__(256) void k_fold_proj(
    const float* __restrict__ pW, const float* __restrict__ pb,
    const float* __restrict__ mW, short* __restrict__ W2T, float* __restrict__ b2)
{
    if (blockIdx.x < 64) {
        int o = blockIdx.x * 256 + threadIdx.x;
        int i = o >> 7, c = o & 127;   // i = k (input), c = n (output col)
        float acc = 0.f;
        for (int k = 0; k < 128; ++k) acc = fmaf(pW[i * 128 + k], mW[k * 128 + c], acc);
        W2T[c * 128 + i] = f2bf(acc);
    } else {
        int c = threadIdx.x;
        if (c < 128) {
            float acc = 0.f;
            for (int k = 0; k < 128; ++k) acc = fmaf(pb[k], mW[k * 128 + c], acc);
            b2[c] = acc;
        }
    }
}

// ---------------------------------------------------------------------------
// Weight prep (per depth): bf16 [n][k] layouts.
// W1T (mlp1) 512x128, W2Tm (mlp2) 128x512, cwb conv [9][128 co][256 ci]... (as before),
// qWT 128x128, kvWT 256x128.
__global__ __launch_bounds__(256) void k_prep(
    const float* __restrict__ f1W, const float* __restrict__ f2W,
    const float* __restrict__ convW, const float* __restrict__ qW,
    const float* __restrict__ kvW,
    short* __restrict__ W1T, short* __restrict__ W2Tm, short* __restrict__ cwb,
    short* __restrict__ qWT, short* __restrict__ kvWT)
{
    int idx = blockIdx.x * 256 + threadIdx.x;
    if (idx < 65536) {
        int n = idx >> 7, k = idx & 127;
        W1T[idx] = f2bf(f1W[k * 512 + n]);
    } else if (idx < 131072) {
        int j = idx - 65536;
        int n = j >> 9, k = j & 511;
        W2Tm[j] = f2bf(f2W[k * 128 + n]);
    } else if (idx < 425984) {
        int j = idx - 131072;  // 0..294911
        int ci = j & 255;
        int co = (j >> 8) & 127;
        int k9 = j >> 15;
        cwb[j] = f2bf(convW[(co * 256 + ci) * 9 + k9]);
    } else if (idx < 442368) {
        int j = idx - 425984;
        int n = j >> 7, k = j & 127;
        qWT[j] = f2bf(qW[k * 128 + n]);
    } else if (idx < 475136) {
        int j = idx - 442368;
        int n = j >> 7, k = j & 127;
        kvWT[j] = f2bf(kvW[k * 256 + n]);
    }
}

// ---------------------------------------------------------------------------
// Fused MFMA window attention. One block per (window, branch); 4 waves = 4 heads.
// Q/K/VT via MFMA from global fp32 rows (bf16 in-register) x bf16 [n][k] weights;
// S (K=32, one MFMA step) + softmax + PV (regs) + folded proj + LN + residual.
__global__ __launch_bounds__(256) void k_attn_mfma(
    const float* __restrict__ xh, const float* __restrict__ srcb, const float* __restrict__ tgtb,
    const short* __restrict__ qWT, const float* __restrict__ qb,
    const short* __restrict__ kvWT, const float* __restrict__ kvb,
    const float* __restrict__ relb, const short* __restrict__ W2T, const float* __restrict__ b2,
    const float* __restrict__ g1, const float* __restrict__ b1,
    float* __restrict__ sa, float* __restrict__ ta, int shift)
{
    __shared__ short s_q[64 * 136];      // Q [tok][128] (later: O)
    __shared__ short s_kk[64 * 136];     // K [tok][128]
    __shared__ short s_vt[128 * 72];     // V^T [d][tok]
    __shared__ short s_p[4][16 * 72];    // per-wave P m-tile

    int gid = blockIdx.x;
    int branch = gid >= 1152;
    int wid = branch ? gid - 1152 : gid;
    const float* feat = branch ? tgtb : srcb;
    float* outb = branch ? ta : sa;
    int b = wid / 576;
    int wi = wid - b * 576;
    int wh = wi / 24, ww = wi - wh * 24;

    int tid = threadIdx.x;
    int h = tid >> 6;          // wave == head
    int lane = tid & 63;
    int ln = lane & 15, quad = lane >> 4;
    int ho = h * 32;
    int koff = quad * 8;

    // global row offsets for token = mt*16 + ln (rolled coords)
    size_t rowoff[4];
    #pragma unroll
    for (int mt = 0; mt < 4; ++mt) {
        int tok = mt * 16 + ln;
        int ti = tok >> 3, tj = tok & 7;
        int hh = wh * 8 + ti + shift; if (hh >= 192) hh -= 192;
        int wz = ww * 8 + tj + shift; if (wz >= 192) wz -= 192;
        rowoff[mt] = (((size_t)b * 192 + hh) * 192 + wz) * 128;
    }

    // ---- Q = (X @ qW + qb) * SCALE -> s_q cols [ho, ho+32)
    {
        f32x4 acc[4][2] = {};
        for (int kc = 0; kc < 4; ++kc) {
            s16x8 a[4];
            #pragma unroll
            for (int mt = 0; mt < 4; ++mt) a[mt] = ld8bf(xh + rowoff[mt] + kc * 32 + koff);
            #pragma unroll
            for (int nt = 0; nt < 2; ++nt) {
                s16x8 bfr = *(const s16x8*)(qWT + (ho + nt * 16 + ln) * 128 + kc * 32 + koff);
                #pragma unroll
                for (int mt = 0; mt < 4; ++mt)
                    acc[mt][nt] = __builtin_amdgcn_mfma_f32_16x16x32_bf16(a[mt], bfr, acc[mt][nt], 0, 0, 0);
            }
        }
        #pragma unroll
        for (int nt = 0; nt < 2; ++nt) {
            int col = ho + nt * 16 + ln;
            float bb = qb[col];
            #pragma unroll
            for (int mt = 0; mt < 4; ++mt)
                #pragma unroll
                for (int r = 0; r < 4; ++r)
                    s_q[(mt * 16 + quad * 4 + r) * 136 + col] = f2bf((acc[mt][nt][r] + bb) * SCALEf);
        }
    }

    // ---- K = F @ kvW_k + kvb -> s_kk cols [ho, ho+32)
    {
        f32x4 acc[4][2] = {};
        for (int kc = 0; kc < 4; ++kc) {
            s16x8 a[4];
            #pragma unroll
            for (int mt = 0; mt < 4; ++mt) a[mt] = ld8bf(feat + rowoff[mt] + kc * 32 + koff);
            #pragma unroll
            for (int nt = 0; nt < 2; ++nt) {
                s16x8 bfr = *(const s16x8*)(kvWT + (ho + nt * 16 + ln) * 128 + kc * 32 + koff);
                #pragma unroll
                for (int mt = 0; mt < 4; ++mt)
                    acc[mt][nt] = __builtin_amdgcn_mfma_f32_16x16x32_bf16(a[mt], bfr, acc[mt][nt], 0, 0, 0);
            }
        }
        #pragma unroll
        for (int nt = 0; nt < 2; ++nt) {
            int col = ho + nt * 16 + ln;
            float bb = kvb[col];
            #pragma unroll
            for (int mt = 0; mt < 4; ++mt)
                #pragma unroll
                for (int r = 0; r < 4; ++r)
                    s_kk[(mt * 16 + quad * 4 + r) * 136 + col] = f2bf(acc[mt][nt][r] + bb);
        }
    }

    // ---- V^T: rows d in [ho, ho+32), cols = tokens. A = kvWT rows (128+d), B = F token rows.
    {
        f32x4 acc[2][4] = {};
        for (int kc = 0; kc < 4; ++kc) {
            s16x8 aw[2];
            #pragma unroll
            for (int md = 0; md < 2; ++md)
                aw[md] = *(const s16x8*)(kvWT + (128 + ho + md * 16 + ln) * 128 + kc * 32 + koff);
            #pragma unroll
            for (int nt = 0; nt < 4; ++nt) {
                s16x8 bfr = ld8bf(feat + rowoff[nt] + kc * 32 + koff);
                #pragma unroll
                for (int md = 0; md < 2; ++md)
                    acc[md][nt] = __builtin_amdgcn_mfma_f32_16x16x32_bf16(aw[md], bfr, acc[md][nt], 0, 0, 0);
            }
        }
        #pragma unroll
        for (int md = 0; md < 2; ++md)
            #pragma unroll
            for (int r = 0; r < 4; ++r) {
                int d = ho + md * 16 + quad * 4 + r;
                float bb = kvb[128 + d];
                #pragma unroll
                for (int nt = 0; nt < 4; ++nt)
                    s_vt[d * 72 + nt * 16 + ln] = f2bf(acc[md][nt][r] + bb);
            }
    }

    // ---- S + softmax + PV (per m-tile), O accumulated in registers
    int cnt_k[4];
    if (shift) {
        #pragma unroll
        for (int nt = 0; nt < 4; ++nt) {
            int ktok = nt * 16 + ln;
            cnt_k[nt] = region_code(wh * 8 + (ktok >> 3), ww * 8 + (ktok & 7));
        }
    }
    f32x4 acco[4][2] = {};
    short* pbuf = s_p[h];
    #pragma unroll
    for (int mt = 0; mt < 4; ++mt) {
        s16x8 aq = *(const s16x8*)(s_q + (mt * 16 + ln) * 136 + ho + koff);
        f32x4 s[4];
        #pragma unroll
        for (int nt = 0; nt < 4; ++nt) {
            s16x8 bk = *(const s16x8*)(s_kk + (nt * 16 + ln) * 136 + ho + koff);
            f32x4 z = {};
            s[nt] = __builtin_amdgcn_mfma_f32_16x16x32_bf16(aq, bk, z, 0, 0, 0);
        }
        #pragma unroll
        for (int r = 0; r < 4; ++r) {
            int qtok = mt * 16 + quad * 4 + r;
            int qti = qtok >> 3, qtj = qtok & 7;
            int cq = 0;
            if (shift) cq = region_code(wh * 8 + qti, ww * 8 + qtj);
            float vals[4];
            #pragma unroll
            for (int nt = 0; nt < 4; ++nt) {
                int ktok = nt * 16 + ln;
                int dr = qti - (ktok >> 3) + 7, dc = qtj - (ktok & 7) + 7;
                float v = s[nt][r] + relb[(dr * 15 + dc) * 4 + h];
                if (shift && cq != cnt_k[nt]) v -= 100.0f;
                vals[nt] = v;
            }
            float mx = fmaxf(fmaxf(vals[0], vals[1]), fmaxf(vals[2], vals[3]));
            mx = fmaxf(mx, __shfl_xor(mx, 1));
            mx = fmaxf(mx, __shfl_xor(mx, 2));
            mx = fmaxf(mx, __shfl_xor(mx, 4));
            mx = fmaxf(mx, __shfl_xor(mx, 8));
            float e[4], sum = 0.f;
            #pragma unroll
            for (int nt = 0; nt < 4; ++nt) { e[nt] = __expf(vals[nt] - mx); sum += e[nt]; }
            sum += __shfl_xor(sum, 1);
            sum += __shfl_xor(sum, 2);
            sum += __shfl_xor(sum, 4);
            sum += __shfl_xor(sum, 8);
            float inv = 1.0f / sum;
            #pragma unroll
            for (int nt = 0; nt < 4; ++nt)
                pbuf[(quad * 4 + r) * 72 + nt * 16 + ln] = f2bf(e[nt] * inv);
        }
        // PV: A = pbuf rows (token), B = s_vt rows (d)
        #pragma unroll
        for (int kc2 = 0; kc2 < 2; ++kc2) {
            s16x8 ap = *(const s16x8*)(pbuf + ln * 72 + kc2 * 32 + koff);
            #pragma unroll
            for (int nt2 = 0; nt2 < 2; ++nt2) {
                s16x8 bv = *(const s16x8*)(s_vt + (ho + nt2 * 16 + ln) * 72 + kc2 * 32 + koff);
                acco[mt][nt2] = __builtin_amdgcn_mfma_f32_16x16x32_bf16(ap, bv, acco[mt][nt2], 0, 0, 0);
            }
        }
    }
    // write O into s_q (own head cols; own-wave A-frag reads are done)
    #pragma unroll
    for (int mt = 0; mt < 4; ++mt)
        #pragma unroll
        for (int nt2 = 0; nt2 < 2; ++nt2)
            #pragma unroll
            for (int r = 0; r < 4; ++r)
                s_q[(mt * 16 + quad * 4 + r) * 136 + ho + nt2 * 16 + ln] = f2bf(acco[mt][nt2][r]);
    __syncthreads();

    // ---- proj + LN + residual: wave handles m-tile == h
    {
        f32x4 accp[8] = {};
        for (int kc = 0; kc < 4; ++kc) {
            s16x8 a = *(const s16x8*)(s_q + (h * 16 + ln) * 136 + kc * 32 + koff);
            #pragma unroll
            for (int nt = 0; nt < 8; ++nt) {
                s16x8 bfr = *(const s16x8*)(W2T + (nt * 16 + ln) * 128 + kc * 32 + koff);
                accp[nt] = __builtin_amdgcn_mfma_f32_16x16x32_bf16(a, bfr, accp[nt], 0, 0, 0);
            }
        }
        #pragma unroll
        for (int nt = 0; nt < 8; ++nt) {
            float bb = b2[nt * 16 + ln];
            #pragma unroll
            for (int r = 0; r < 4; ++r) accp[nt][r] += bb;
        }
        #pragma unroll
        for (int r = 0; r < 4; ++r) {
            float sm = 0.f, sq = 0.f;
            #pragma unroll
            for (int nt = 0; nt < 8; ++nt) { float v = accp[nt][r]; sm += v; sq = fmaf(v, v, sq); }
            sm += __shfl_xor(sm, 1); sq += __shfl_xor(sq, 1);
            sm += __shfl_xor(sm, 2); sq += __shfl_xor(sq, 2);
            sm += __shfl_xor(sm, 4); sq += __shfl_xor(sq, 4);
            sm += __shfl_xor(sm, 8); sq += __shfl_xor(sq, 8);
            float mean = sm * (1.0f / 128.0f);
            float var = sq * (1.0f / 128.0f) - mean * mean;
            float rstd = rsqrtf(var + 1e-5f);
            int token = h * 16 + quad * 4 + r;
            int ti = token >> 3, tj = token & 7;
            int hh = wh * 8 + ti + shift; if (hh >= 192) hh -= 192;
            int wz = ww * 8 + tj + shift; if (wz >= 192) wz -= 192;
            size_t rb = (((size_t)b * 192 + hh) * 192 + wz) * 128;
            #pragma unroll
            for (int nt = 0; nt < 8; ++nt) {
                int col = nt * 16 + ln;
                float o = xh[rb + col] + fmaf((accp[nt][r] - mean) * rstd, g1[col], b1[col]);
                outb[rb + col] = o;
            }
        }
    }
}

// ---------------------------------------------------------------------------
// MFMA MLP (unchanged from round 2)
__global__ __launch_bounds__(256) void k_mlp_mfma(
    const float* sab, const float* tab,
    const short* __restrict__ W1T, const float* __restrict__ f1b,
    const short* __restrict__ W2T, const float* __restrict__ f2b,
    const float* __restrict__ g2, const float* __restrict__ b2n,
    short* catb)
{
    __shared__ short s_h[4][16 * 520];
    int w = threadIdx.x >> 6, lane = threadIdx.x & 63;
    int ln = lane & 15, quad = lane >> 4;
    int tok0 = blockIdx.x * 64 + w * 16;
    short* H = s_h[w];

    for (int br = 0; br < 2; ++br) {
        const float* X = br ? tab : sab;
        s16x8 a1[4];
        const float* xrow = X + (size_t)(tok0 + ln) * 128 + quad * 8;
        #pragma unroll
        for (int kc = 0; kc < 4; ++kc) a1[kc] = ld8bf(xrow + kc * 32);
        for (int nt = 0; nt < 32; ++nt) {
            f32x4 acc = {0.f, 0.f, 0.f, 0.f};
            const short* wb = W1T + (nt * 16 + ln) * 128 + quad * 8;
            #pragma unroll
            for (int kc = 0; kc < 4; ++kc) {
                s16x8 bfr = *(const s16x8*)(wb + kc * 32);
                acc = __builtin_amdgcn_mfma_f32_16x16x32_bf16(a1[kc], bfr, acc, 0, 0, 0);
            }
            float bb = f1b[nt * 16 + ln];
            #pragma unroll
            for (int r = 0; r < 4; ++r)
                H[(quad * 4 + r) * 520 + nt * 16 + ln] = f2bf(gelu_f(acc[r] + bb));
        }
        f32x4 acc2[8];
        #pragma unroll
        for (int nt = 0; nt < 8; ++nt) acc2[nt] = (f32x4){0.f, 0.f, 0.f, 0.f};
        for (int kc = 0; kc < 16; ++kc) {
            s16x8 afr = *(const s16x8*)(H + ln * 520 + kc * 32 + quad * 8);
            #pragma unroll
            for (int nt = 0; nt < 8; ++nt) {
                s16x8 bfr = *(const s16x8*)(W2T + (nt * 16 + ln) * 512 + kc * 32 + quad * 8);
                acc2[nt] = __builtin_amdgcn_mfma_f32_16x16x32_bf16(afr, bfr, acc2[nt], 0, 0, 0);
            }
        }
        #pragma unroll
        for (int nt = 0; nt < 8; ++nt) {
            float bb = f2b[nt * 16 + ln];
            #pragma unroll
            for (int r = 0; r < 4; ++r) acc2[nt][r] += bb;
        }
        #pragma unroll
        for (int r = 0; r < 4; ++r) {
            float smv = 0.f, sqv = 0.f;
            #pragma unroll
            for (int nt = 0; nt < 8; ++nt) { float v = acc2[nt][r]; smv += v; sqv = fmaf(v, v, sqv); }
            smv += __shfl_xor(smv, 1); sqv += __shfl_xor(sqv, 1);
            smv += __shfl_xor(smv, 2); sqv += __shfl_xor(sqv, 2);
            smv += __shfl_xor(smv, 4); sqv += __shfl_xor(sqv, 4);
            smv += __shfl_xor(smv, 8); sqv += __shfl_xor(sqv, 8);
            float mean = smv * (1.0f / 128.0f);
            float var = sqv * (1.0f / 128.0f) - mean * mean;
            float rstd = rsqrtf(var + 1e-5f);
            int row = tok0 + quad * 4 + r;
            const float* xr = X + (size_t)row * 128;
            short* cb = catb + (size_t)row * 256 + br * 128;
            #pragma unroll
            for (int nt = 0; nt < 8; ++nt) {
                int col = nt * 16 + ln;
                float o = xr[col] + fmaf((acc2[nt][r] - mean) * rstd, g2[col], b2n[col]);
                cb[col] = f2bf(o);
            }
        }
    }
}

// ---------------------------------------------------------------------------
// MFMA implicit-GEMM conv3x3 (unchanged from round 2)
__global__ __launch_bounds__(256) void k_conv_mfma(
    const short* __restrict__ catb, const short* __restrict__ cwb,
    const float* __restrict__ bias, const float* __restrict__ pa,
    float* __restrict__ out, int nchw)
{
    __shared__ short s_in[3 * 34 * 264];
    __shared__ float s_out[128 * 33];
    int gid = blockIdx.x;
    int b = gid / 1152;
    int r0 = gid - b * 1152;
    int h = r0 / 6;
    int w0 = (r0 - h * 6) * 32;
    int tid = threadIdx.x;

    for (int idx = tid; idx < 3264; idx += 256) {
        int row = idx >> 5, seg = idx & 31;
        int dh = row / 34, wc34 = row - dh * 34;
        int hh = h - 1 + dh;
        int wc = w0 - 1 + wc34;
        uint4 v = make_uint4(0u, 0u, 0u, 0u);
        if (hh >= 0 && hh < 192 && wc >= 0 && wc < 192)
            v = *(const uint4*)(catb + (((size_t)b * 192 + hh) * 192 + wc) * 256 + seg * 8);
        *(uint4*)(&s_in[(dh * 34 + wc34) * 264 + seg * 8]) = v;
    }
    __syncthreads();

    int w = tid >> 6, lane = tid & 63;
    int ln = lane & 15, quad = lane >> 4;
    int mt = w & 1, ng = w >> 1;
    f32x4 acc[4];
    #pragma unroll
    for (int nt = 0; nt < 4; ++nt) acc[nt] = (f32x4){0.f, 0.f, 0.f, 0.f};

    #pragma unroll
    for (int kh = 0; kh < 3; ++kh) {
        #pragma unroll
        for (int kw = 0; kw < 3; ++kw) {
            int pc = mt * 16 + ln + kw;
            const short* abase = &s_in[(kh * 34 + pc) * 264];
            const short* wbase = cwb + (size_t)((kh * 3 + kw) * 128 + ng * 64) * 256;
            for (int kc = 0; kc < 8; ++kc) {
                s16x8 afr = *(const s16x8*)(abase + kc * 32 + quad * 8);
                #pragma unroll
                for (int nt = 0; nt < 4; ++nt) {
                    s16x8 bfr = *(const s16x8*)(wbase + (nt * 16 + ln) * 256 + kc * 32 + quad * 8);
                    acc[nt] = __builtin_amdgcn_mfma_f32_16x16x32_bf16(afr, bfr, acc[nt], 0, 0, 0);
                }
            }
        }
    }

    if (nchw) {
        #pragma unroll
        for (int nt = 0; nt < 4; ++nt) {
            int co = ng * 64 + nt * 16 + ln;
            float bs = bias[co], pv = pa[co];
            #pragma unroll
            for (int r = 0; r < 4; ++r) {
                int pos = mt * 16 + quad * 4 + r;
                float v = acc[nt][r] + bs;
                v = (v >= 0.f) ? v : pv * v;
                s_out[co * 33 + pos] = v;
            }
        }
        __syncthreads();
        for (int idx = tid; idx < 1024; idx += 256) {
            int co = idx >> 3, sg = idx & 7;
            float4 v;
            v.x = s_out[co * 33 + sg * 4 + 0];
            v.y = s_out[co * 33 + sg * 4 + 1];
            v.z = s_out[co * 33 + sg * 4 + 2];
            v.w = s_out[co * 33 + sg * 4 + 3];
            *(float4*)(out + (((size_t)b * 128 + co) * 192 + h) * 192 + w0 + sg * 4) = v;
        }
    } else {
        #pragma unroll
        for (int nt = 0; nt < 4; ++nt) {
            int co = ng * 64 + nt * 16 + ln;
            float bs = bias[co], pv = pa[co];
            #pragma unroll
            for (int r = 0; r < 4; ++r) {
                int pos = mt * 16 + quad * 4 + r;
                float v = acc[nt][r] + bs;
                v = (v >= 0.f) ? v : pv * v;
                out[(((size_t)b * 192 + h) * 192 + w0 + pos) * 128 + co] = v;
            }
        }
    }
}

// ---------------------------------------------------------------------------
extern "C" void kernel_launch(void* const* d_in, const int* in_sizes, int n_in,
                              void* d_out, int out_size, void* d_ws, size_t ws_size,
                              hipStream_t stream)
{
    const float* x    = (const float*)d_in[0];
    const float* src  = (const float*)d_in[1];
    const float* tgt  = (const float*)d_in[2];
    const float* qW   = (const float*)d_in[3];
    const float* qb   = (const float*)d_in[4];
    const float* kvW  = (const float*)d_in[5];
    const float* kvb  = (const float*)d_in[6];
    const float* pW   = (const float*)d_in[7];
    const float* pb   = (const float*)d_in[8];
    const float* relb = (const float*)d_in[9];
    const float* mW   = (const float*)d_in[10];
    const float* n1g  = (const float*)d_in[11];
    const float* n1b  = (const float*)d_in[12];
    const float* f1W  = (const float*)d_in[13];
    const float* f1b  = (const float*)d_in[14];
    const float* f2W  = (const float*)d_in[15];
    const float* f2b  = (const float*)d_in[16];
    const float* n2g  = (const float*)d_in[17];
    const float* n2b  = (const float*)d_in[18];
    const float* convW= (const float*)d_in[19];
    const float* convb= (const float*)d_in[20];
    const float* pa   = (const float*)d_in[21];
    float* out = (float*)d_out;

    const size_t FR = (size_t)2 * 192 * 192 * 128;
    float* ws   = (float*)d_ws;
    float* xh   = ws;
    float* srch = ws + FR;
    float* tgth = ws + 2 * FR;
    float* sab  = ws + 3 * FR;
    float* tab  = ws + 4 * FR;
    float* b2   = ws + 5 * FR;               // 128 floats
    short* W1T  = (short*)(b2 + 128);        // 65536
    short* W2Tm = W1T + 65536;               // 65536
    short* cwb  = W2Tm + 65536;              // 294912
    short* qWT  = cwb + 294912;              // 16384
    short* kvWT = qWT + 16384;               // 32768
    short* W2Tp = kvWT + 32768;              // 16384
    short* catb = (short*)sab;               // bf16 cat buffer aliases sab

    k_transpose<<<dim3(1152, 8, 3), 256, 0, stream>>>(x, src, tgt, xh, srch, tgth);

    for (int d = 0; d < 2; ++d) {
        int shift = d ? 4 : 0;
        k_fold_proj<<<65, 256, 0, stream>>>(pW + d * 16384, pb + d * 128, mW + d * 16384, W2Tp, b2);
        k_prep<<<1856, 256, 0, stream>>>(f1W + d * 65536, f2W + d * 65536,
                                         convW + d * 294912, qW + d * 16384, kvW + d * 32768,
                                         W1T, W2Tm, cwb, qWT, kvWT);
        k_attn_mfma<<<2304, 256, 0, stream>>>(xh, srch, tgth,
            qWT, qb + d * 128, kvWT, kvb + d * 256,
            relb + d * 900, W2Tp, b2, n1g + d * 128, n1b + d * 128, sab, tab, shift);
        k_mlp_mfma<<<1152, 256, 0, stream>>>(sab, tab, W1T, f1b + d * 512,
            W2Tm, f2b + d * 128, n2g + d * 128, n2b + d * 128, catb);
        k_conv_mfma<<<2304, 256, 0, stream>>>(catb, cwb, convb + d * 128, pa + d * 128,
            d == 1 ? out : xh, d == 1 ? 1 : 0);
    }
}

// Round 4
// 1801.377 us; speedup vs baseline: 12.1233x; 1.3529x over previous
//
#include <hip/hip_runtime.h>
#include <math.h>

// B=2, C=128, H=192, W=192, NH=4, WS=8, HD=32, N=64, SHIFT=4, HID=512, NWIN=576
#define SCALEf 0.1767766952966369f  // 32^-0.5

typedef short s16x8 __attribute__((ext_vector_type(8)));
typedef float f32x4 __attribute__((ext_vector_type(4)));

__device__ __forceinline__ short f2bf(float f) {
    unsigned u = __float_as_uint(f);
    u += 0x7FFF + ((u >> 16) & 1);
    return (short)(u >> 16);
}
__device__ __forceinline__ float gelu_f(float u) {
    float z = 1.5957691216057308f * u * (1.0f + 0.044715f * u * u);
    return u / (1.0f + __expf(-z));
}
__device__ __forceinline__ s16x8 ld8bf(const float* p) {
    float4 u0 = *(const float4*)p;
    float4 u1 = *(const float4*)(p + 4);
    s16x8 a;
    a[0] = f2bf(u0.x); a[1] = f2bf(u0.y); a[2] = f2bf(u0.z); a[3] = f2bf(u0.w);
    a[4] = f2bf(u1.x); a[5] = f2bf(u1.y); a[6] = f2bf(u1.z); a[7] = f2bf(u1.w);
    return a;
}
__device__ __forceinline__ int region_code(int h, int w) {
    return ((h < 184) ? 0 : (h < 188 ? 3 : 6)) + ((w < 184) ? 0 : (w < 188 ? 1 : 2));
}

// ---------------------------------------------------------------------------
// NCHW -> BHWC transpose for x / source / target
__global__ __launch_bounds__(256) void k_transpose(
    const float* __restrict__ x, const float* __restrict__ s, const float* __restrict__ t,
    float* __restrict__ xo, float* __restrict__ so, float* __restrict__ to)
{
    int which = blockIdx.z;
    const float* in = which == 0 ? x : (which == 1 ? s : t);
    float* out = which == 0 ? xo : (which == 1 ? so : to);
    __shared__ float tile[32][33];
    int by = blockIdx.y;
    int b = by >> 2;
    int c0 = (by & 3) * 32;
    int p0 = blockIdx.x * 32;
    int tx = threadIdx.x & 31;
    int ty = threadIdx.x >> 5;
    const float* ip = in + (size_t)b * 128 * 36864;
    #pragma unroll
    for (int k = 0; k < 4; ++k) {
        int c = c0 + ty + 8 * k;
        tile[ty + 8 * k][tx] = ip[(size_t)c * 36864 + p0 + tx];
    }
    __syncthreads();
    float* op = out + (size_t)b * 36864 * 128;
    #pragma unroll
    for (int k = 0; k < 4; ++k) {
        int p = p0 + ty + 8 * k;
        op[(size_t)p * 128 + c0 + tx] = tile[tx][ty + 8 * k];
    }
}

// ---------------------------------------------------------------------------
// Fold projection: W2 = pW @ mW; write bf16 W2T[n][k] + fp32 b2 = pb @ mW
__global__ __launch_bounds__(256) void k_fold_proj(
    const float* __restrict__ pW, const float* __restrict__ pb,
    const float* __restrict__ mW, short* __restrict__ W2T, float* __restrict__ b2)
{
    if (blockIdx.x < 64) {
        int o = blockIdx.x * 256 + threadIdx.x;
        int i = o >> 7, c = o & 127;
        float acc = 0.f;
        for (int k = 0; k < 128; ++k) acc = fmaf(pW[i * 128 + k], mW[k * 128 + c], acc);
        W2T[c * 128 + i] = f2bf(acc);
    } else {
        int c = threadIdx.x;
        if (c < 128) {
            float acc = 0.f;
            for (int k = 0; k < 128; ++k) acc = fmaf(pb[k], mW[k * 128 + c], acc);
            b2[c] = acc;
        }
    }
}

// ---------------------------------------------------------------------------
// Weight prep (per depth): bf16 [n][k] layouts.
__global__ __launch_bounds__(256) void k_prep(
    const float* __restrict__ f1W, const float* __restrict__ f2W,
    const float* __restrict__ convW, const float* __restrict__ qW,
    const float* __restrict__ kvW,
    short* __restrict__ W1T, short* __restrict__ W2Tm, short* __restrict__ cwb,
    short* __restrict__ qWT, short* __restrict__ kvWT)
{
    int idx = blockIdx.x * 256 + threadIdx.x;
    if (idx < 65536) {
        int n = idx >> 7, k = idx & 127;
        W1T[idx] = f2bf(f1W[k * 512 + n]);
    } else if (idx < 131072) {
        int j = idx - 65536;
        int n = j >> 9, k = j & 511;
        W2Tm[j] = f2bf(f2W[k * 128 + n]);
    } else if (idx < 425984) {
        int j = idx - 131072;
        int ci = j & 255;
        int co = (j >> 8) & 127;
        int k9 = j >> 15;
        cwb[j] = f2bf(convW[(co * 256 + ci) * 9 + k9]);
    } else if (idx < 442368) {
        int j = idx - 425984;
        int n = j >> 7, k = j & 127;
        qWT[j] = f2bf(qW[k * 128 + n]);
    } else if (idx < 475136) {
        int j = idx - 442368;
        int n = j >> 7, k = j & 127;
        kvWT[j] = f2bf(kvW[k * 256 + n]);
    }
}

// ---------------------------------------------------------------------------
// Fused MFMA window attention (unchanged from round 3)
__global__ __launch_bounds__(256) void k_attn_mfma(
    const float* __restrict__ xh, const float* __restrict__ srcb, const float* __restrict__ tgtb,
    const short* __restrict__ qWT, const float* __restrict__ qb,
    const short* __restrict__ kvWT, const float* __restrict__ kvb,
    const float* __restrict__ relb, const short* __restrict__ W2T, const float* __restrict__ b2,
    const float* __restrict__ g1, const float* __restrict__ b1,
    float* __restrict__ sa, float* __restrict__ ta, int shift)
{
    __shared__ short s_q[64 * 136];
    __shared__ short s_kk[64 * 136];
    __shared__ short s_vt[128 * 72];
    __shared__ short s_p[4][16 * 72];

    int gid = blockIdx.x;
    int branch = gid >= 1152;
    int wid = branch ? gid - 1152 : gid;
    const float* feat = branch ? tgtb : srcb;
    float* outb = branch ? ta : sa;
    int b = wid / 576;
    int wi = wid - b * 576;
    int wh = wi / 24, ww = wi - wh * 24;

    int tid = threadIdx.x;
    int h = tid >> 6;
    int lane = tid & 63;
    int ln = lane & 15, quad = lane >> 4;
    int ho = h * 32;
    int koff = quad * 8;

    size_t rowoff[4];
    #pragma unroll
    for (int mt = 0; mt < 4; ++mt) {
        int tok = mt * 16 + ln;
        int ti = tok >> 3, tj = tok & 7;
        int hh = wh * 8 + ti + shift; if (hh >= 192) hh -= 192;
        int wz = ww * 8 + tj + shift; if (wz >= 192) wz -= 192;
        rowoff[mt] = (((size_t)b * 192 + hh) * 192 + wz) * 128;
    }

    {
        f32x4 acc[4][2] = {};
        for (int kc = 0; kc < 4; ++kc) {
            s16x8 a[4];
            #pragma unroll
            for (int mt = 0; mt < 4; ++mt) a[mt] = ld8bf(xh + rowoff[mt] + kc * 32 + koff);
            #pragma unroll
            for (int nt = 0; nt < 2; ++nt) {
                s16x8 bfr = *(const s16x8*)(qWT + (ho + nt * 16 + ln) * 128 + kc * 32 + koff);
                #pragma unroll
                for (int mt = 0; mt < 4; ++mt)
                    acc[mt][nt] = __builtin_amdgcn_mfma_f32_16x16x32_bf16(a[mt], bfr, acc[mt][nt], 0, 0, 0);
            }
        }
        #pragma unroll
        for (int nt = 0; nt < 2; ++nt) {
            int col = ho + nt * 16 + ln;
            float bb = qb[col];
            #pragma unroll
            for (int mt = 0; mt < 4; ++mt)
                #pragma unroll
                for (int r = 0; r < 4; ++r)
                    s_q[(mt * 16 + quad * 4 + r) * 136 + col] = f2bf((acc[mt][nt][r] + bb) * SCALEf);
        }
    }

    {
        f32x4 acc[4][2] = {};
        for (int kc = 0; kc < 4; ++kc) {
            s16x8 a[4];
            #pragma unroll
            for (int mt = 0; mt < 4; ++mt) a[mt] = ld8bf(feat + rowoff[mt] + kc * 32 + koff);
            #pragma unroll
            for (int nt = 0; nt < 2; ++nt) {
                s16x8 bfr = *(const s16x8*)(kvWT + (ho + nt * 16 + ln) * 128 + kc * 32 + koff);
                #pragma unroll
                for (int mt = 0; mt < 4; ++mt)
                    acc[mt][nt] = __builtin_amdgcn_mfma_f32_16x16x32_bf16(a[mt], bfr, acc[mt][nt], 0, 0, 0);
            }
        }
        #pragma unroll
        for (int nt = 0; nt < 2; ++nt) {
            int col = ho + nt * 16 + ln;
            float bb = kvb[col];
            #pragma unroll
            for (int mt = 0; mt < 4; ++mt)
                #pragma unroll
                for (int r = 0; r < 4; ++r)
                    s_kk[(mt * 16 + quad * 4 + r) * 136 + col] = f2bf(acc[mt][nt][r] + bb);
        }
    }

    {
        f32x4 acc[2][4] = {};
        for (int kc = 0; kc < 4; ++kc) {
            s16x8 aw[2];
            #pragma unroll
            for (int md = 0; md < 2; ++md)
                aw[md] = *(const s16x8*)(kvWT + (128 + ho + md * 16 + ln) * 128 + kc * 32 + koff);
            #pragma unroll
            for (int nt = 0; nt < 4; ++nt) {
                s16x8 bfr = ld8bf(feat + rowoff[nt] + kc * 32 + koff);
                #pragma unroll
                for (int md = 0; md < 2; ++md)
                    acc[md][nt] = __builtin_amdgcn_mfma_f32_16x16x32_bf16(aw[md], bfr, acc[md][nt], 0, 0, 0);
            }
        }
        #pragma unroll
        for (int md = 0; md < 2; ++md)
            #pragma unroll
            for (int r = 0; r < 4; ++r) {
                int d = ho + md * 16 + quad * 4 + r;
                float bb = kvb[128 + d];
                #pragma unroll
                for (int nt = 0; nt < 4; ++nt)
                    s_vt[d * 72 + nt * 16 + ln] = f2bf(acc[md][nt][r] + bb);
            }
    }

    int cnt_k[4];
    if (shift) {
        #pragma unroll
        for (int nt = 0; nt < 4; ++nt) {
            int ktok = nt * 16 + ln;
            cnt_k[nt] = region_code(wh * 8 + (ktok >> 3), ww * 8 + (ktok & 7));
        }
    }
    f32x4 acco[4][2] = {};
    short* pbuf = s_p[h];
    #pragma unroll
    for (int mt = 0; mt < 4; ++mt) {
        s16x8 aq = *(const s16x8*)(s_q + (mt * 16 + ln) * 136 + ho + koff);
        f32x4 s[4];
        #pragma unroll
        for (int nt = 0; nt < 4; ++nt) {
            s16x8 bk = *(const s16x8*)(s_kk + (nt * 16 + ln) * 136 + ho + koff);
            f32x4 z = {};
            s[nt] = __builtin_amdgcn_mfma_f32_16x16x32_bf16(aq, bk, z, 0, 0, 0);
        }
        #pragma unroll
        for (int r = 0; r < 4; ++r) {
            int qtok = mt * 16 + quad * 4 + r;
            int qti = qtok >> 3, qtj = qtok & 7;
            int cq = 0;
            if (shift) cq = region_code(wh * 8 + qti, ww * 8 + qtj);
            float vals[4];
            #pragma unroll
            for (int nt = 0; nt < 4; ++nt) {
                int ktok = nt * 16 + ln;
                int dr = qti - (ktok >> 3) + 7, dc = qtj - (ktok & 7) + 7;
                float v = s[nt][r] + relb[(dr * 15 + dc) * 4 + h];
                if (shift && cq != cnt_k[nt]) v -= 100.0f;
                vals[nt] = v;
            }
            float mx = fmaxf(fmaxf(vals[0], vals[1]), fmaxf(vals[2], vals[3]));
            mx = fmaxf(mx, __shfl_xor(mx, 1));
            mx = fmaxf(mx, __shfl_xor(mx, 2));
            mx = fmaxf(mx, __shfl_xor(mx, 4));
            mx = fmaxf(mx, __shfl_xor(mx, 8));
            float e[4], sum = 0.f;
            #pragma unroll
            for (int nt = 0; nt < 4; ++nt) { e[nt] = __expf(vals[nt] - mx); sum += e[nt]; }
            sum += __shfl_xor(sum, 1);
            sum += __shfl_xor(sum, 2);
            sum += __shfl_xor(sum, 4);
            sum += __shfl_xor(sum, 8);
            float inv = 1.0f / sum;
            #pragma unroll
            for (int nt = 0; nt < 4; ++nt)
                pbuf[(quad * 4 + r) * 72 + nt * 16 + ln] = f2bf(e[nt] * inv);
        }
        #pragma unroll
        for (int kc2 = 0; kc2 < 2; ++kc2) {
            s16x8 ap = *(const s16x8*)(pbuf + ln * 72 + kc2 * 32 + koff);
            #pragma unroll
            for (int nt2 = 0; nt2 < 2; ++nt2) {
                s16x8 bv = *(const s16x8*)(s_vt + (ho + nt2 * 16 + ln) * 72 + kc2 * 32 + koff);
                acco[mt][nt2] = __builtin_amdgcn_mfma_f32_16x16x32_bf16(ap, bv, acco[mt][nt2], 0, 0, 0);
            }
        }
    }
    #pragma unroll
    for (int mt = 0; mt < 4; ++mt)
        #pragma unroll
        for (int nt2 = 0; nt2 < 2; ++nt2)
            #pragma unroll
            for (int r = 0; r < 4; ++r)
                s_q[(mt * 16 + quad * 4 + r) * 136 + ho + nt2 * 16 + ln] = f2bf(acco[mt][nt2][r]);
    __syncthreads();

    {
        f32x4 accp[8] = {};
        for (int kc = 0; kc < 4; ++kc) {
            s16x8 a = *(const s16x8*)(s_q + (h * 16 + ln) * 136 + kc * 32 + koff);
            #pragma unroll
            for (int nt = 0; nt < 8; ++nt) {
                s16x8 bfr = *(const s16x8*)(W2T + (nt * 16 + ln) * 128 + kc * 32 + koff);
                accp[nt] = __builtin_amdgcn_mfma_f32_16x16x32_bf16(a, bfr, accp[nt], 0, 0, 0);
            }
        }
        #pragma unroll
        for (int nt = 0; nt < 8; ++nt) {
            float bb = b2[nt * 16 + ln];
            #pragma unroll
            for (int r = 0; r < 4; ++r) accp[nt][r] += bb;
        }
        #pragma unroll
        for (int r = 0; r < 4; ++r) {
            float sm = 0.f, sq = 0.f;
            #pragma unroll
            for (int nt = 0; nt < 8; ++nt) { float v = accp[nt][r]; sm += v; sq = fmaf(v, v, sq); }
            sm += __shfl_xor(sm, 1); sq += __shfl_xor(sq, 1);
            sm += __shfl_xor(sm, 2); sq += __shfl_xor(sq, 2);
            sm += __shfl_xor(sm, 4); sq += __shfl_xor(sq, 4);
            sm += __shfl_xor(sm, 8); sq += __shfl_xor(sq, 8);
            float mean = sm * (1.0f / 128.0f);
            float var = sq * (1.0f / 128.0f) - mean * mean;
            float rstd = rsqrtf(var + 1e-5f);
            int token = h * 16 + quad * 4 + r;
            int ti = token >> 3, tj = token & 7;
            int hh = wh * 8 + ti + shift; if (hh >= 192) hh -= 192;
            int wz = ww * 8 + tj + shift; if (wz >= 192) wz -= 192;
            size_t rb = (((size_t)b * 192 + hh) * 192 + wz) * 128;
            #pragma unroll
            for (int nt = 0; nt < 8; ++nt) {
                int col = nt * 16 + ln;
                float o = xh[rb + col] + fmaf((accp[nt][r] - mean) * rstd, g1[col], b1[col]);
                outb[rb + col] = o;
            }
        }
    }
}

// ---------------------------------------------------------------------------
// MFMA MLP v2: register-blocked GEMMs + coalesced epilogue.
// Block = 64 tokens, 4 waves. GEMM1: wave n-slice 128 cols x 64 tok (32 acc).
// GEMM2: wave n-slice 32 cols x 64 tok (8 acc). Epilogue: fp32 via LDS,
// LN with 4-lane groups, each lane writes 64 B contiguous bf16 to catb.
__global__ __launch_bounds__(256) void k_mlp_mfma(
    const float* sab, const float* tab,
    const short* __restrict__ W1T, const float* __restrict__ f1b,
    const short* __restrict__ W2T, const float* __restrict__ f2b,
    const float* __restrict__ g2, const float* __restrict__ b2n,
    short* catb)
{
    __shared__ short s_h[64 * 520];          // H bf16 [64][520]
    float* Hf = (float*)s_h;                 // fp32 view [64][132] for epilogue
    int tid = threadIdx.x;
    int w = tid >> 6, lane = tid & 63;
    int ln = lane & 15, quad = lane >> 4;
    int koff = quad * 8;
    int tok0 = blockIdx.x * 64;

    for (int br = 0; br < 2; ++br) {
        const float* X = br ? tab : sab;

        // ---- GEMM1: K=128, M=64 (4 mt), N-slice = w*128..+128 (8 nt)
        f32x4 acc[4][8] = {};
        for (int kc = 0; kc < 4; ++kc) {
            s16x8 a[4];
            #pragma unroll
            for (int mt = 0; mt < 4; ++mt)
                a[mt] = ld8bf(X + (size_t)(tok0 + mt * 16 + ln) * 128 + kc * 32 + koff);
            s16x8 bfr[8];
            #pragma unroll
            for (int nt = 0; nt < 8; ++nt)
                bfr[nt] = *(const s16x8*)(W1T + (size_t)(w * 128 + nt * 16 + ln) * 128 + kc * 32 + koff);
            #pragma unroll
            for (int nt = 0; nt < 8; ++nt)
                #pragma unroll
                for (int mt = 0; mt < 4; ++mt)
                    acc[mt][nt] = __builtin_amdgcn_mfma_f32_16x16x32_bf16(a[mt], bfr[nt], acc[mt][nt], 0, 0, 0);
        }
        #pragma unroll
        for (int nt = 0; nt < 8; ++nt) {
            int col = w * 128 + nt * 16 + ln;
            float bb = f1b[col];
            #pragma unroll
            for (int mt = 0; mt < 4; ++mt)
                #pragma unroll
                for (int r = 0; r < 4; ++r)
                    s_h[(mt * 16 + quad * 4 + r) * 520 + col] = f2bf(gelu_f(acc[mt][nt][r] + bb));
        }
        __syncthreads();

        // ---- GEMM2: K=512, M=64 (4 mt), N-slice = w*32..+32 (2 nt)
        f32x4 acc2[4][2] = {};
        for (int kc = 0; kc < 16; ++kc) {
            s16x8 a2[4];
            #pragma unroll
            for (int mt = 0; mt < 4; ++mt)
                a2[mt] = *(const s16x8*)(s_h + (mt * 16 + ln) * 520 + kc * 32 + koff);
            s16x8 b2f[2];
            #pragma unroll
            for (int nt = 0; nt < 2; ++nt)
                b2f[nt] = *(const s16x8*)(W2T + (size_t)(w * 32 + nt * 16 + ln) * 512 + kc * 32 + koff);
            #pragma unroll
            for (int nt = 0; nt < 2; ++nt)
                #pragma unroll
                for (int mt = 0; mt < 4; ++mt)
                    acc2[mt][nt] = __builtin_amdgcn_mfma_f32_16x16x32_bf16(a2[mt], b2f[nt], acc2[mt][nt], 0, 0, 0);
        }
        __syncthreads();   // all H reads complete before fp32 overwrite
        #pragma unroll
        for (int nt = 0; nt < 2; ++nt) {
            int col = w * 32 + nt * 16 + ln;
            float bb = f2b[col];
            #pragma unroll
            for (int mt = 0; mt < 4; ++mt)
                #pragma unroll
                for (int r = 0; r < 4; ++r)
                    Hf[(mt * 16 + quad * 4 + r) * 132 + col] = acc2[mt][nt][r] + bb;
        }
        __syncthreads();

        // ---- LN + residual + coalesced catb write
        {
            int t16 = lane >> 2, cg = lane & 3;
            int row = w * 16 + t16;             // local token 0..63
            const float* hrow = Hf + row * 132 + cg * 32;
            float hv[32];
            #pragma unroll
            for (int j4 = 0; j4 < 8; ++j4)
                *(float4*)(hv + j4 * 4) = *(const float4*)(hrow + j4 * 4);
            float sm = 0.f, sq = 0.f;
            #pragma unroll
            for (int j = 0; j < 32; ++j) { sm += hv[j]; sq = fmaf(hv[j], hv[j], sq); }
            sm += __shfl_xor(sm, 1); sq += __shfl_xor(sq, 1);
            sm += __shfl_xor(sm, 2); sq += __shfl_xor(sq, 2);
            float mean = sm * (1.0f / 128.0f);
            float var = sq * (1.0f / 128.0f) - mean * mean;
            float rstd = rsqrtf(var + 1e-5f);
            const float* xr = X + (size_t)(tok0 + row) * 128 + cg * 32;
            short* cb = catb + (size_t)(tok0 + row) * 256 + br * 128 + cg * 32;
            s16x8 obuf[4];
            #pragma unroll
            for (int j = 0; j < 32; ++j) {
                int col = cg * 32 + j;
                float o = xr[j] + fmaf((hv[j] - mean) * rstd, g2[col], b2n[col]);
                obuf[j >> 3][j & 7] = f2bf(o);
            }
            #pragma unroll
            for (int j4 = 0; j4 < 4; ++j4)
                *(s16x8*)(cb + j4 * 8) = obuf[j4];
        }
        __syncthreads();   // protect H region before next branch
    }
}

// ---------------------------------------------------------------------------
// MFMA implicit-GEMM conv3x3 (unchanged)
__global__ __launch_bounds__(256) void k_conv_mfma(
    const short* __restrict__ catb, const short* __restrict__ cwb,
    const float* __restrict__ bias, const float* __restrict__ pa,
    float* __restrict__ out, int nchw)
{
    __shared__ short s_in[3 * 34 * 264];
    __shared__ float s_out[128 * 33];
    int gid = blockIdx.x;
    int b = gid / 1152;
    int r0 = gid - b * 1152;
    int h = r0 / 6;
    int w0 = (r0 - h * 6) * 32;
    int tid = threadIdx.x;

    for (int idx = tid; idx < 3264; idx += 256) {
        int row = idx >> 5, seg = idx & 31;
        int dh = row / 34, wc34 = row - dh * 34;
        int hh = h - 1 + dh;
        int wc = w0 - 1 + wc34;
        uint4 v = make_uint4(0u, 0u, 0u, 0u);
        if (hh >= 0 && hh < 192 && wc >= 0 && wc < 192)
            v = *(const uint4*)(catb + (((size_t)b * 192 + hh) * 192 + wc) * 256 + seg * 8);
        *(uint4*)(&s_in[(dh * 34 + wc34) * 264 + seg * 8]) = v;
    }
    __syncthreads();

    int w = tid >> 6, lane = tid & 63;
    int ln = lane & 15, quad = lane >> 4;
    int mt = w & 1, ng = w >> 1;
    f32x4 acc[4];
    #pragma unroll
    for (int nt = 0; nt < 4; ++nt) acc[nt] = (f32x4){0.f, 0.f, 0.f, 0.f};

    #pragma unroll
    for (int kh = 0; kh < 3; ++kh) {
        #pragma unroll
        for (int kw = 0; kw < 3; ++kw) {
            int pc = mt * 16 + ln + kw;
            const short* abase = &s_in[(kh * 34 + pc) * 264];
            const short* wbase = cwb + (size_t)((kh * 3 + kw) * 128 + ng * 64) * 256;
            for (int kc = 0; kc < 8; ++kc) {
                s16x8 afr = *(const s16x8*)(abase + kc * 32 + quad * 8);
                #pragma unroll
                for (int nt = 0; nt < 4; ++nt) {
                    s16x8 bfr = *(const s16x8*)(wbase + (nt * 16 + ln) * 256 + kc * 32 + quad * 8);
                    acc[nt] = __builtin_amdgcn_mfma_f32_16x16x32_bf16(afr, bfr, acc[nt], 0, 0, 0);
                }
            }
        }
    }

    if (nchw) {
        #pragma unroll
        for (int nt = 0; nt < 4; ++nt) {
            int co = ng * 64 + nt * 16 + ln;
            float bs = bias[co], pv = pa[co];
            #pragma unroll
            for (int r = 0; r < 4; ++r) {
                int pos = mt * 16 + quad * 4 + r;
                float v = acc[nt][r] + bs;
                v = (v >= 0.f) ? v : pv * v;
                s_out[co * 33 + pos] = v;
            }
        }
        __syncthreads();
        for (int idx = tid; idx < 1024; idx += 256) {
            int co = idx >> 3, sg = idx & 7;
            float4 v;
            v.x = s_out[co * 33 + sg * 4 + 0];
            v.y = s_out[co * 33 + sg * 4 + 1];
            v.z = s_out[co * 33 + sg * 4 + 2];
            v.w = s_out[co * 33 + sg * 4 + 3];
            *(float4*)(out + (((size_t)b * 128 + co) * 192 + h) * 192 + w0 + sg * 4) = v;
        }
    } else {
        #pragma unroll
        for (int nt = 0; nt < 4; ++nt) {
            int co = ng * 64 + nt * 16 + ln;
            float bs = bias[co], pv = pa[co];
            #pragma unroll
            for (int r = 0; r < 4; ++r) {
                int pos = mt * 16 + quad * 4 + r;
                float v = acc[nt][r] + bs;
                v = (v >= 0.f) ? v : pv * v;
                out[(((size_t)b * 192 + h) * 192 + w0 + pos) * 128 + co] = v;
            }
        }
    }
}

// ---------------------------------------------------------------------------
extern "C" void kernel_launch(void* const* d_in, const int* in_sizes, int n_in,
                              void* d_out, int out_size, void* d_ws, size_t ws_size,
                              hipStream_t stream)
{
    const float* x    = (const float*)d_in[0];
    const float* src  = (const float*)d_in[1];
    const float* tgt  = (const float*)d_in[2];
    const float* qW   = (const float*)d_in[3];
    const float* qb   = (const float*)d_in[4];
    const float* kvW  = (const float*)d_in[5];
    const float* kvb  = (const float*)d_in[6];
    const float* pW   = (const float*)d_in[7];
    const float* pb   = (const float*)d_in[8];
    const float* relb = (const float*)d_in[9];
    const float* mW   = (const float*)d_in[10];
    const float* n1g  = (const float*)d_in[11];
    const float* n1b  = (const float*)d_in[12];
    const float* f1W  = (const float*)d_in[13];
    const float* f1b  = (const float*)d_in[14];
    const float* f2W  = (const float*)d_in[15];
    const float* f2b  = (const float*)d_in[16];
    const float* n2g  = (const float*)d_in[17];
    const float* n2b  = (const float*)d_in[18];
    const float* convW= (const float*)d_in[19];
    const float* convb= (const float*)d_in[20];
    const float* pa   = (const float*)d_in[21];
    float* out = (float*)d_out;

    const size_t FR = (size_t)2 * 192 * 192 * 128;
    float* ws   = (float*)d_ws;
    float* xh   = ws;
    float* srch = ws + FR;
    float* tgth = ws + 2 * FR;
    float* sab  = ws + 3 * FR;
    float* tab  = ws + 4 * FR;
    float* b2   = ws + 5 * FR;
    short* W1T  = (short*)(b2 + 128);
    short* W2Tm = W1T + 65536;
    short* cwb  = W2Tm + 65536;
    short* qWT  = cwb + 294912;
    short* kvWT = qWT + 16384;
    short* W2Tp = kvWT + 32768;
    short* catb = (short*)sab;

    k_transpose<<<dim3(1152, 8, 3), 256, 0, stream>>>(x, src, tgt, xh, srch, tgth);

    for (int d = 0; d < 2; ++d) {
        int shift = d ? 4 : 0;
        k_fold_proj<<<65, 256, 0, stream>>>(pW + d * 16384, pb + d * 128, mW + d * 16384, W2Tp, b2);
        k_prep<<<1856, 256, 0, stream>>>(f1W + d * 65536, f2W + d * 65536,
                                         convW + d * 294912, qW + d * 16384, kvW + d * 32768,
                                         W1T, W2Tm, cwb, qWT, kvWT);
        k_attn_mfma<<<2304, 256, 0, stream>>>(xh, srch, tgth,
            qWT, qb + d * 128, kvWT, kvb + d * 256,
            relb + d * 900, W2Tp, b2, n1g + d * 128, n1b + d * 128, sab, tab, shift);
        k_mlp_mfma<<<1152, 256, 0, stream>>>(sab, tab, W1T, f1b + d * 512,
            W2Tm, f2b + d * 128, n2g + d * 128, n2b + d * 128, catb);
        k_conv_mfma<<<2304, 256, 0, stream>>>(catb, cwb, convb + d * 128, pa + d * 128,
            d == 1 ? out : xh, d == 1 ? 1 : 0);
    }
}

// Round 5
// 1486.259 us; speedup vs baseline: 14.6937x; 1.2120x over previous
//
#include <hip/hip_runtime.h>
#include <math.h>

// B=2, C=128, H=192, W=192, NH=4, WS=8, HD=32, N=64, SHIFT=4, HID=512, NWIN=576
#define SCALEf 0.1767766952966369f  // 32^-0.5

typedef short s16x8 __attribute__((ext_vector_type(8)));
typedef float f32x4 __attribute__((ext_vector_type(4)));

__device__ __forceinline__ short f2bf(float f) {
    unsigned u = __float_as_uint(f);
    u += 0x7FFF + ((u >> 16) & 1);
    return (short)(u >> 16);
}
__device__ __forceinline__ float gelu_f(float u) {
    float z = 1.5957691216057308f * u * (1.0f + 0.044715f * u * u);
    return u / (1.0f + __expf(-z));
}
__device__ __forceinline__ s16x8 ld8bf(const float* p) {
    float4 u0 = *(const float4*)p;
    float4 u1 = *(const float4*)(p + 4);
    s16x8 a;
    a[0] = f2bf(u0.x); a[1] = f2bf(u0.y); a[2] = f2bf(u0.z); a[3] = f2bf(u0.w);
    a[4] = f2bf(u1.x); a[5] = f2bf(u1.y); a[6] = f2bf(u1.z); a[7] = f2bf(u1.w);
    return a;
}
__device__ __forceinline__ int region_code(int h, int w) {
    return ((h < 184) ? 0 : (h < 188 ? 3 : 6)) + ((w < 184) ? 0 : (w < 188 ? 1 : 2));
}

// ---------------------------------------------------------------------------
// NCHW -> BHWC transpose for x / source / target
__global__ __launch_bounds__(256) void k_transpose(
    const float* __restrict__ x, const float* __restrict__ s, const float* __restrict__ t,
    float* __restrict__ xo, float* __restrict__ so, float* __restrict__ to)
{
    int which = blockIdx.z;
    const float* in = which == 0 ? x : (which == 1 ? s : t);
    float* out = which == 0 ? xo : (which == 1 ? so : to);
    __shared__ float tile[32][33];
    int by = blockIdx.y;
    int b = by >> 2;
    int c0 = (by & 3) * 32;
    int p0 = blockIdx.x * 32;
    int tx = threadIdx.x & 31;
    int ty = threadIdx.x >> 5;
    const float* ip = in + (size_t)b * 128 * 36864;
    #pragma unroll
    for (int k = 0; k < 4; ++k) {
        int c = c0 + ty + 8 * k;
        tile[ty + 8 * k][tx] = ip[(size_t)c * 36864 + p0 + tx];
    }
    __syncthreads();
    float* op = out + (size_t)b * 36864 * 128;
    #pragma unroll
    for (int k = 0; k < 4; ++k) {
        int p = p0 + ty + 8 * k;
        op[(size_t)p * 128 + c0 + tx] = tile[tx][ty + 8 * k];
    }
}

// ---------------------------------------------------------------------------
// Fold projection: W2 = pW @ mW; write bf16 W2T[n][k] + fp32 b2 = pb @ mW
__global__ __launch_bounds__(256) void k_fold_proj(
    const float* __restrict__ pW, const float* __restrict__ pb,
    const float* __restrict__ mW, short* __restrict__ W2T, float* __restrict__ b2)
{
    if (blockIdx.x < 64) {
        int o = blockIdx.x * 256 + threadIdx.x;
        int i = o >> 7, c = o & 127;
        float acc = 0.f;
        for (int k = 0; k < 128; ++k) acc = fmaf(pW[i * 128 + k], mW[k * 128 + c], acc);
        W2T[c * 128 + i] = f2bf(acc);
    } else {
        int c = threadIdx.x;
        if (c < 128) {
            float acc = 0.f;
            for (int k = 0; k < 128; ++k) acc = fmaf(pb[k], mW[k * 128 + c], acc);
            b2[c] = acc;
        }
    }
}

// ---------------------------------------------------------------------------
// Weight prep (per depth): bf16 [n][k] layouts.
__global__ __launch_bounds__(256) void k_prep(
    const float* __restrict__ f1W, const float* __restrict__ f2W,
    const float* __restrict__ convW, const float* __restrict__ qW,
    const float* __restrict__ kvW,
    short* __restrict__ W1T, short* __restrict__ W2Tm, short* __restrict__ cwb,
    short* __restrict__ qWT, short* __restrict__ kvWT)
{
    int idx = blockIdx.x * 256 + threadIdx.x;
    if (idx < 65536) {
        int n = idx >> 7, k = idx & 127;
        W1T[idx] = f2bf(f1W[k * 512 + n]);
    } else if (idx < 131072) {
        int j = idx - 65536;
        int n = j >> 9, k = j & 511;
        W2Tm[j] = f2bf(f2W[k * 128 + n]);
    } else if (idx < 425984) {
        int j = idx - 131072;
        int ci = j & 255;
        int co = (j >> 8) & 127;
        int k9 = j >> 15;
        cwb[j] = f2bf(convW[(co * 256 + ci) * 9 + k9]);
    } else if (idx < 442368) {
        int j = idx - 425984;
        int n = j >> 7, k = j & 127;
        qWT[j] = f2bf(qW[k * 128 + n]);
    } else if (idx < 475136) {
        int j = idx - 442368;
        int n = j >> 7, k = j & 127;
        kvWT[j] = f2bf(kvW[k * 256 + n]);
    }
}

// ---------------------------------------------------------------------------
// Fused MFMA window attention (unchanged from round 3)
__global__ __launch_bounds__(256) void k_attn_mfma(
    const float* __restrict__ xh, const float* __restrict__ srcb, const float* __restrict__ tgtb,
    const short* __restrict__ qWT, const float* __restrict__ qb,
    const short* __restrict__ kvWT, const float* __restrict__ kvb,
    const float* __restrict__ relb, const short* __restrict__ W2T, const float* __restrict__ b2,
    const float* __restrict__ g1, const float* __restrict__ b1,
    float* __restrict__ sa, float* __restrict__ ta, int shift)
{
    __shared__ short s_q[64 * 136];
    __shared__ short s_kk[64 * 136];
    __shared__ short s_vt[128 * 72];
    __shared__ short s_p[4][16 * 72];

    int gid = blockIdx.x;
    int branch = gid >= 1152;
    int wid = branch ? gid - 1152 : gid;
    const float* feat = branch ? tgtb : srcb;
    float* outb = branch ? ta : sa;
    int b = wid / 576;
    int wi = wid - b * 576;
    int wh = wi / 24, ww = wi - wh * 24;

    int tid = threadIdx.x;
    int h = tid >> 6;
    int lane = tid & 63;
    int ln = lane & 15, quad = lane >> 4;
    int ho = h * 32;
    int koff = quad * 8;

    size_t rowoff[4];
    #pragma unroll
    for (int mt = 0; mt < 4; ++mt) {
        int tok = mt * 16 + ln;
        int ti = tok >> 3, tj = tok & 7;
        int hh = wh * 8 + ti + shift; if (hh >= 192) hh -= 192;
        int wz = ww * 8 + tj + shift; if (wz >= 192) wz -= 192;
        rowoff[mt] = (((size_t)b * 192 + hh) * 192 + wz) * 128;
    }

    {
        f32x4 acc[4][2] = {};
        for (int kc = 0; kc < 4; ++kc) {
            s16x8 a[4];
            #pragma unroll
            for (int mt = 0; mt < 4; ++mt) a[mt] = ld8bf(xh + rowoff[mt] + kc * 32 + koff);
            #pragma unroll
            for (int nt = 0; nt < 2; ++nt) {
                s16x8 bfr = *(const s16x8*)(qWT + (ho + nt * 16 + ln) * 128 + kc * 32 + koff);
                #pragma unroll
                for (int mt = 0; mt < 4; ++mt)
                    acc[mt][nt] = __builtin_amdgcn_mfma_f32_16x16x32_bf16(a[mt], bfr, acc[mt][nt], 0, 0, 0);
            }
        }
        #pragma unroll
        for (int nt = 0; nt < 2; ++nt) {
            int col = ho + nt * 16 + ln;
            float bb = qb[col];
            #pragma unroll
            for (int mt = 0; mt < 4; ++mt)
                #pragma unroll
                for (int r = 0; r < 4; ++r)
                    s_q[(mt * 16 + quad * 4 + r) * 136 + col] = f2bf((acc[mt][nt][r] + bb) * SCALEf);
        }
    }

    {
        f32x4 acc[4][2] = {};
        for (int kc = 0; kc < 4; ++kc) {
            s16x8 a[4];
            #pragma unroll
            for (int mt = 0; mt < 4; ++mt) a[mt] = ld8bf(feat + rowoff[mt] + kc * 32 + koff);
            #pragma unroll
            for (int nt = 0; nt < 2; ++nt) {
                s16x8 bfr = *(const s16x8*)(kvWT + (ho + nt * 16 + ln) * 128 + kc * 32 + koff);
                #pragma unroll
                for (int mt = 0; mt < 4; ++mt)
                    acc[mt][nt] = __builtin_amdgcn_mfma_f32_16x16x32_bf16(a[mt], bfr, acc[mt][nt], 0, 0, 0);
            }
        }
        #pragma unroll
        for (int nt = 0; nt < 2; ++nt) {
            int col = ho + nt * 16 + ln;
            float bb = kvb[col];
            #pragma unroll
            for (int mt = 0; mt < 4; ++mt)
                #pragma unroll
                for (int r = 0; r < 4; ++r)
                    s_kk[(mt * 16 + quad * 4 + r) * 136 + col] = f2bf(acc[mt][nt][r] + bb);
        }
    }

    {
        f32x4 acc[2][4] = {};
        for (int kc = 0; kc < 4; ++kc) {
            s16x8 aw[2];
            #pragma unroll
            for (int md = 0; md < 2; ++md)
                aw[md] = *(const s16x8*)(kvWT + (128 + ho + md * 16 + ln) * 128 + kc * 32 + koff);
            #pragma unroll
            for (int nt = 0; nt < 4; ++nt) {
                s16x8 bfr = ld8bf(feat + rowoff[nt] + kc * 32 + koff);
                #pragma unroll
                for (int md = 0; md < 2; ++md)
                    acc[md][nt] = __builtin_amdgcn_mfma_f32_16x16x32_bf16(aw[md], bfr, acc[md][nt], 0, 0, 0);
            }
        }
        #pragma unroll
        for (int md = 0; md < 2; ++md)
            #pragma unroll
            for (int r = 0; r < 4; ++r) {
                int d = ho + md * 16 + quad * 4 + r;
                float bb = kvb[128 + d];
                #pragma unroll
                for (int nt = 0; nt < 4; ++nt)
                    s_vt[d * 72 + nt * 16 + ln] = f2bf(acc[md][nt][r] + bb);
            }
    }

    int cnt_k[4];
    if (shift) {
        #pragma unroll
        for (int nt = 0; nt < 4; ++nt) {
            int ktok = nt * 16 + ln;
            cnt_k[nt] = region_code(wh * 8 + (ktok >> 3), ww * 8 + (ktok & 7));
        }
    }
    f32x4 acco[4][2] = {};
    short* pbuf = s_p[h];
    #pragma unroll
    for (int mt = 0; mt < 4; ++mt) {
        s16x8 aq = *(const s16x8*)(s_q + (mt * 16 + ln) * 136 + ho + koff);
        f32x4 s[4];
        #pragma unroll
        for (int nt = 0; nt < 4; ++nt) {
            s16x8 bk = *(const s16x8*)(s_kk + (nt * 16 + ln) * 136 + ho + koff);
            f32x4 z = {};
            s[nt] = __builtin_amdgcn_mfma_f32_16x16x32_bf16(aq, bk, z, 0, 0, 0);
        }
        #pragma unroll
        for (int r = 0; r < 4; ++r) {
            int qtok = mt * 16 + quad * 4 + r;
            int qti = qtok >> 3, qtj = qtok & 7;
            int cq = 0;
            if (shift) cq = region_code(wh * 8 + qti, ww * 8 + qtj);
            float vals[4];
            #pragma unroll
            for (int nt = 0; nt < 4; ++nt) {
                int ktok = nt * 16 + ln;
                int dr = qti - (ktok >> 3) + 7, dc = qtj - (ktok & 7) + 7;
                float v = s[nt][r] + relb[(dr * 15 + dc) * 4 + h];
                if (shift && cq != cnt_k[nt]) v -= 100.0f;
                vals[nt] = v;
            }
            float mx = fmaxf(fmaxf(vals[0], vals[1]), fmaxf(vals[2], vals[3]));
            mx = fmaxf(mx, __shfl_xor(mx, 1));
            mx = fmaxf(mx, __shfl_xor(mx, 2));
            mx = fmaxf(mx, __shfl_xor(mx, 4));
            mx = fmaxf(mx, __shfl_xor(mx, 8));
            float e[4], sum = 0.f;
            #pragma unroll
            for (int nt = 0; nt < 4; ++nt) { e[nt] = __expf(vals[nt] - mx); sum += e[nt]; }
            sum += __shfl_xor(sum, 1);
            sum += __shfl_xor(sum, 2);
            sum += __shfl_xor(sum, 4);
            sum += __shfl_xor(sum, 8);
            float inv = 1.0f / sum;
            #pragma unroll
            for (int nt = 0; nt < 4; ++nt)
                pbuf[(quad * 4 + r) * 72 + nt * 16 + ln] = f2bf(e[nt] * inv);
        }
        #pragma unroll
        for (int kc2 = 0; kc2 < 2; ++kc2) {
            s16x8 ap = *(const s16x8*)(pbuf + ln * 72 + kc2 * 32 + koff);
            #pragma unroll
            for (int nt2 = 0; nt2 < 2; ++nt2) {
                s16x8 bv = *(const s16x8*)(s_vt + (ho + nt2 * 16 + ln) * 72 + kc2 * 32 + koff);
                acco[mt][nt2] = __builtin_amdgcn_mfma_f32_16x16x32_bf16(ap, bv, acco[mt][nt2], 0, 0, 0);
            }
        }
    }
    #pragma unroll
    for (int mt = 0; mt < 4; ++mt)
        #pragma unroll
        for (int nt2 = 0; nt2 < 2; ++nt2)
            #pragma unroll
            for (int r = 0; r < 4; ++r)
                s_q[(mt * 16 + quad * 4 + r) * 136 + ho + nt2 * 16 + ln] = f2bf(acco[mt][nt2][r]);
    __syncthreads();

    {
        f32x4 accp[8] = {};
        for (int kc = 0; kc < 4; ++kc) {
            s16x8 a = *(const s16x8*)(s_q + (h * 16 + ln) * 136 + kc * 32 + koff);
            #pragma unroll
            for (int nt = 0; nt < 8; ++nt) {
                s16x8 bfr = *(const s16x8*)(W2T + (nt * 16 + ln) * 128 + kc * 32 + koff);
                accp[nt] = __builtin_amdgcn_mfma_f32_16x16x32_bf16(a, bfr, accp[nt], 0, 0, 0);
            }
        }
        #pragma unroll
        for (int nt = 0; nt < 8; ++nt) {
            float bb = b2[nt * 16 + ln];
            #pragma unroll
            for (int r = 0; r < 4; ++r) accp[nt][r] += bb;
        }
        #pragma unroll
        for (int r = 0; r < 4; ++r) {
            float sm = 0.f, sq = 0.f;
            #pragma unroll
            for (int nt = 0; nt < 8; ++nt) { float v = accp[nt][r]; sm += v; sq = fmaf(v, v, sq); }
            sm += __shfl_xor(sm, 1); sq += __shfl_xor(sq, 1);
            sm += __shfl_xor(sm, 2); sq += __shfl_xor(sq, 2);
            sm += __shfl_xor(sm, 4); sq += __shfl_xor(sq, 4);
            sm += __shfl_xor(sm, 8); sq += __shfl_xor(sq, 8);
            float mean = sm * (1.0f / 128.0f);
            float var = sq * (1.0f / 128.0f) - mean * mean;
            float rstd = rsqrtf(var + 1e-5f);
            int token = h * 16 + quad * 4 + r;
            int ti = token >> 3, tj = token & 7;
            int hh = wh * 8 + ti + shift; if (hh >= 192) hh -= 192;
            int wz = ww * 8 + tj + shift; if (wz >= 192) wz -= 192;
            size_t rb = (((size_t)b * 192 + hh) * 192 + wz) * 128;
            #pragma unroll
            for (int nt = 0; nt < 8; ++nt) {
                int col = nt * 16 + ln;
                float o = xh[rb + col] + fmaf((accp[nt][r] - mean) * rstd, g1[col], b1[col]);
                outb[rb + col] = o;
            }
        }
    }
}

// ---------------------------------------------------------------------------
// MFMA MLP v2 (unchanged from round 4)
__global__ __launch_bounds__(256) void k_mlp_mfma(
    const float* sab, const float* tab,
    const short* __restrict__ W1T, const float* __restrict__ f1b,
    const short* __restrict__ W2T, const float* __restrict__ f2b,
    const float* __restrict__ g2, const float* __restrict__ b2n,
    short* catb)
{
    __shared__ short s_h[64 * 520];
    float* Hf = (float*)s_h;
    int tid = threadIdx.x;
    int w = tid >> 6, lane = tid & 63;
    int ln = lane & 15, quad = lane >> 4;
    int koff = quad * 8;
    int tok0 = blockIdx.x * 64;

    for (int br = 0; br < 2; ++br) {
        const float* X = br ? tab : sab;

        f32x4 acc[4][8] = {};
        for (int kc = 0; kc < 4; ++kc) {
            s16x8 a[4];
            #pragma unroll
            for (int mt = 0; mt < 4; ++mt)
                a[mt] = ld8bf(X + (size_t)(tok0 + mt * 16 + ln) * 128 + kc * 32 + koff);
            s16x8 bfr[8];
            #pragma unroll
            for (int nt = 0; nt < 8; ++nt)
                bfr[nt] = *(const s16x8*)(W1T + (size_t)(w * 128 + nt * 16 + ln) * 128 + kc * 32 + koff);
            #pragma unroll
            for (int nt = 0; nt < 8; ++nt)
                #pragma unroll
                for (int mt = 0; mt < 4; ++mt)
                    acc[mt][nt] = __builtin_amdgcn_mfma_f32_16x16x32_bf16(a[mt], bfr[nt], acc[mt][nt], 0, 0, 0);
        }
        #pragma unroll
        for (int nt = 0; nt < 8; ++nt) {
            int col = w * 128 + nt * 16 + ln;
            float bb = f1b[col];
            #pragma unroll
            for (int mt = 0; mt < 4; ++mt)
                #pragma unroll
                for (int r = 0; r < 4; ++r)
                    s_h[(mt * 16 + quad * 4 + r) * 520 + col] = f2bf(gelu_f(acc[mt][nt][r] + bb));
        }
        __syncthreads();

        f32x4 acc2[4][2] = {};
        for (int kc = 0; kc < 16; ++kc) {
            s16x8 a2[4];
            #pragma unroll
            for (int mt = 0; mt < 4; ++mt)
                a2[mt] = *(const s16x8*)(s_h + (mt * 16 + ln) * 520 + kc * 32 + koff);
            s16x8 b2f[2];
            #pragma unroll
            for (int nt = 0; nt < 2; ++nt)
                b2f[nt] = *(const s16x8*)(W2T + (size_t)(w * 32 + nt * 16 + ln) * 512 + kc * 32 + koff);
            #pragma unroll
            for (int nt = 0; nt < 2; ++nt)
                #pragma unroll
                for (int mt = 0; mt < 4; ++mt)
                    acc2[mt][nt] = __builtin_amdgcn_mfma_f32_16x16x32_bf16(a2[mt], b2f[nt], acc2[mt][nt], 0, 0, 0);
        }
        __syncthreads();
        #pragma unroll
        for (int nt = 0; nt < 2; ++nt) {
            int col = w * 32 + nt * 16 + ln;
            float bb = f2b[col];
            #pragma unroll
            for (int mt = 0; mt < 4; ++mt)
                #pragma unroll
                for (int r = 0; r < 4; ++r)
                    Hf[(mt * 16 + quad * 4 + r) * 132 + col] = acc2[mt][nt][r] + bb;
        }
        __syncthreads();

        {
            int t16 = lane >> 2, cg = lane & 3;
            int row = w * 16 + t16;
            const float* hrow = Hf + row * 132 + cg * 32;
            float hv[32];
            #pragma unroll
            for (int j4 = 0; j4 < 8; ++j4)
                *(float4*)(hv + j4 * 4) = *(const float4*)(hrow + j4 * 4);
            float sm = 0.f, sq = 0.f;
            #pragma unroll
            for (int j = 0; j < 32; ++j) { sm += hv[j]; sq = fmaf(hv[j], hv[j], sq); }
            sm += __shfl_xor(sm, 1); sq += __shfl_xor(sq, 1);
            sm += __shfl_xor(sm, 2); sq += __shfl_xor(sq, 2);
            float mean = sm * (1.0f / 128.0f);
            float var = sq * (1.0f / 128.0f) - mean * mean;
            float rstd = rsqrtf(var + 1e-5f);
            const float* xr = X + (size_t)(tok0 + row) * 128 + cg * 32;
            short* cb = catb + (size_t)(tok0 + row) * 256 + br * 128 + cg * 32;
            s16x8 obuf[4];
            #pragma unroll
            for (int j = 0; j < 32; ++j) {
                int col = cg * 32 + j;
                float o = xr[j] + fmaf((hv[j] - mean) * rstd, g2[col], b2n[col]);
                obuf[j >> 3][j & 7] = f2bf(o);
            }
            #pragma unroll
            for (int j4 = 0; j4 < 4; ++j4)
                *(s16x8*)(cb + j4 * 8) = obuf[j4];
        }
        __syncthreads();
    }
}

// ---------------------------------------------------------------------------
// MFMA implicit-GEMM conv3x3 v2: block = 64 positions (2 rows x 32 cols) x 128 cout.
// Wave: all M=64 (4 mt) x 32-cout slice (2 nt) -> 8 indep MFMAs per kc step,
// B:MFMA = 1:4. Patch 4x34x256 bf16 in LDS (71.8 KB, 2 blocks/CU).
// NCHW epilogue transposes through LDS aliased onto the patch.
__global__ __launch_bounds__(256) void k_conv_mfma(
    const short* __restrict__ catb, const short* __restrict__ cwb,
    const float* __restrict__ bias, const float* __restrict__ pa,
    float* __restrict__ out, int nchw)
{
    __shared__ short s_in[136 * 264];   // 71808 B; aliased as fp32 s_out in NCHW epilogue
    int gid = blockIdx.x;
    int b = gid / 576;
    int r0 = gid - b * 576;
    int hp = r0 / 6;
    int wt = r0 - hp * 6;
    int h0 = hp * 2, w0 = wt * 32;
    int tid = threadIdx.x;

    // stage 4 x 34 x 256 bf16 patch (rows h0-1..h0+2, cols w0-1..w0+32)
    for (int idx = tid; idx < 4352; idx += 256) {
        int row = idx >> 5, seg = idx & 31;
        int dh = row / 34, wc34 = row - dh * 34;
        int hh = h0 - 1 + dh;
        int wc = w0 - 1 + wc34;
        uint4 v = make_uint4(0u, 0u, 0u, 0u);
        if (hh >= 0 && hh < 192 && wc >= 0 && wc < 192)
            v = *(const uint4*)(catb + (((size_t)b * 192 + hh) * 192 + wc) * 256 + seg * 8);
        *(uint4*)(&s_in[row * 264 + seg * 8]) = v;
    }
    __syncthreads();

    int w = tid >> 6, lane = tid & 63;
    int ln = lane & 15, quad = lane >> 4;
    f32x4 acc[4][2] = {};

    #pragma unroll
    for (int kh = 0; kh < 3; ++kh) {
        #pragma unroll
        for (int kw = 0; kw < 3; ++kw) {
            const short* wbase = cwb + (size_t)((kh * 3 + kw) * 128 + w * 32) * 256;
            const short* ab[4];
            #pragma unroll
            for (int mt = 0; mt < 4; ++mt) {
                int prow = ((mt >> 1) + kh) * 34 + (mt & 1) * 16 + ln + kw;
                ab[mt] = s_in + prow * 264 + quad * 8;
            }
            for (int kc = 0; kc < 8; ++kc) {
                s16x8 bfr[2];
                #pragma unroll
                for (int nt = 0; nt < 2; ++nt)
                    bfr[nt] = *(const s16x8*)(wbase + (nt * 16 + ln) * 256 + kc * 32 + quad * 8);
                s16x8 afr[4];
                #pragma unroll
                for (int mt = 0; mt < 4; ++mt)
                    afr[mt] = *(const s16x8*)(ab[mt] + kc * 32);
                #pragma unroll
                for (int nt = 0; nt < 2; ++nt)
                    #pragma unroll
                    for (int mt = 0; mt < 4; ++mt)
                        acc[mt][nt] = __builtin_amdgcn_mfma_f32_16x16x32_bf16(afr[mt], bfr[nt], acc[mt][nt], 0, 0, 0);
            }
        }
    }

    if (!nchw) {
        #pragma unroll
        for (int nt = 0; nt < 2; ++nt) {
            int co = w * 32 + nt * 16 + ln;
            float bs = bias[co], pv = pa[co];
            #pragma unroll
            for (int mt = 0; mt < 4; ++mt) {
                int pr = mt >> 1;
                #pragma unroll
                for (int r = 0; r < 4; ++r) {
                    int pw = (mt & 1) * 16 + quad * 4 + r;
                    float v = acc[mt][nt][r] + bs;
                    v = (v >= 0.f) ? v : pv * v;
                    out[(((size_t)b * 192 + h0 + pr) * 192 + w0 + pw) * 128 + co] = v;
                }
            }
        }
    } else {
        __syncthreads();                 // all s_in reads done before alias overwrite
        float* s_out = (float*)s_in;     // [128][65]
        #pragma unroll
        for (int nt = 0; nt < 2; ++nt) {
            int co = w * 32 + nt * 16 + ln;
            float bs = bias[co], pv = pa[co];
            #pragma unroll
            for (int mt = 0; mt < 4; ++mt) {
                int pos0 = (mt >> 1) * 32 + (mt & 1) * 16 + quad * 4;
                #pragma unroll
                for (int r = 0; r < 4; ++r) {
                    float v = acc[mt][nt][r] + bs;
                    v = (v >= 0.f) ? v : pv * v;
                    s_out[co * 65 + pos0 + r] = v;
                }
            }
        }
        __syncthreads();
        for (int idx = tid; idx < 2048; idx += 256) {
            int co = idx >> 4;
            int pr = (idx >> 3) & 1;
            int sg = idx & 7;
            const float* sp = s_out + co * 65 + pr * 32 + sg * 4;
            float4 v = make_float4(sp[0], sp[1], sp[2], sp[3]);
            *(float4*)(out + (((size_t)b * 128 + co) * 192 + h0 + pr) * 192 + w0 + sg * 4) = v;
        }
    }
}

// ---------------------------------------------------------------------------
extern "C" void kernel_launch(void* const* d_in, const int* in_sizes, int n_in,
                              void* d_out, int out_size, void* d_ws, size_t ws_size,
                              hipStream_t stream)
{
    const float* x    = (const float*)d_in[0];
    const float* src  = (const float*)d_in[1];
    const float* tgt  = (const float*)d_in[2];
    const float* qW   = (const float*)d_in[3];
    const float* qb   = (const float*)d_in[4];
    const float* kvW  = (const float*)d_in[5];
    const float* kvb  = (const float*)d_in[6];
    const float* pW   = (const float*)d_in[7];
    const float* pb   = (const float*)d_in[8];
    const float* relb = (const float*)d_in[9];
    const float* mW   = (const float*)d_in[10];
    const float* n1g  = (const float*)d_in[11];
    const float* n1b  = (const float*)d_in[12];
    const float* f1W  = (const float*)d_in[13];
    const float* f1b  = (const float*)d_in[14];
    const float* f2W  = (const float*)d_in[15];
    const float* f2b  = (const float*)d_in[16];
    const float* n2g  = (const float*)d_in[17];
    const float* n2b  = (const float*)d_in[18];
    const float* convW= (const float*)d_in[19];
    const float* convb= (const float*)d_in[20];
    const float* pa   = (const float*)d_in[21];
    float* out = (float*)d_out;

    const size_t FR = (size_t)2 * 192 * 192 * 128;
    float* ws   = (float*)d_ws;
    float* xh   = ws;
    float* srch = ws + FR;
    float* tgth = ws + 2 * FR;
    float* sab  = ws + 3 * FR;
    float* tab  = ws + 4 * FR;
    float* b2   = ws + 5 * FR;
    short* W1T  = (short*)(b2 + 128);
    short* W2Tm = W1T + 65536;
    short* cwb  = W2Tm + 65536;
    short* qWT  = cwb + 294912;
    short* kvWT = qWT + 16384;
    short* W2Tp = kvWT + 32768;
    short* catb = (short*)sab;

    k_transpose<<<dim3(1152, 8, 3), 256, 0, stream>>>(x, src, tgt, xh, srch, tgth);

    for (int d = 0; d < 2; ++d) {
        int shift = d ? 4 : 0;
        k_fold_proj<<<65, 256, 0, stream>>>(pW + d * 16384, pb + d * 128, mW + d * 16384, W2Tp, b2);
        k_prep<<<1856, 256, 0, stream>>>(f1W + d * 65536, f2W + d * 65536,
                                         convW + d * 294912, qW + d * 16384, kvW + d * 32768,
                                         W1T, W2Tm, cwb, qWT, kvWT);
        k_attn_mfma<<<2304, 256, 0, stream>>>(xh, srch, tgth,
            qWT, qb + d * 128, kvWT, kvb + d * 256,
            relb + d * 900, W2Tp, b2, n1g + d * 128, n1b + d * 128, sab, tab, shift);
        k_mlp_mfma<<<1152, 256, 0, stream>>>(sab, tab, W1T, f1b + d * 512,
            W2Tm, f2b + d * 128, n2g + d * 128, n2b + d * 128, catb);
        k_conv_mfma<<<1152, 256, 0, stream>>>(catb, cwb, convb + d * 128, pa + d * 128,
            d == 1 ? out : xh, d == 1 ? 1 : 0);
    }
}